// Round 1
// baseline (3136.892 us; speedup 1.0000x reference)
//
#include <hip/hip_runtime.h>

#define B_ 4
#define C_ 256
#define R_ 256
#define M_ 40
#define NCLS 21        // NUM_CLASSES + 1
#define ROI_ 7
#define G_ 14          // ROI * SR
#define NROI_TOT 3072  // B * 3 * R
#define PROPS_PER_IMG 768
#define POOL_LD 50     // 49 padded to 50 (even -> 8B-aligned float2 rows)
#define FCK 12544      // C_ * 49

// ---------------------------------------------------------------------------
// Fused cls-head: one block (256 threads) per roi.
//   phase 1: per-axis bilinear coeffs (threads 0..27)
//   phase 2: roi-align, thread = channel, pooled -> LDS [256][50]
//   phase 3: conv3x3 zero-pad, thread = out-channel, 49 accs in regs
//   phase 4: relu + FC(12544->21) partial per thread, wave+LDS reduce
// ---------------------------------------------------------------------------
__global__ __launch_bounds__(256) void cls_head_kernel(
    const float* __restrict__ f3, const float* __restrict__ f4,
    const float* __restrict__ f5, const float* __restrict__ p3,
    const float* __restrict__ p4, const float* __restrict__ p5,
    const float* __restrict__ conv_w, const float* __restrict__ conv_b,
    const float* __restrict__ fc_w, const float* __restrict__ fc_b,
    float* __restrict__ out) {
  __shared__ float s_pool[C_ * POOL_LD];
  __shared__ int s_iy0[G_], s_iy1[G_], s_ix0[G_], s_ix1[G_];
  __shared__ float s_ly[G_], s_lx[G_], s_vy[G_], s_vx[G_];
  __shared__ float s_red[NCLS * 4];

  const int g = blockIdx.x;
  const int b = g / PROPS_PER_IMG;
  const int rem = g - b * PROPS_PER_IMG;
  const int lvl = rem >> 8;
  const int r = rem & 255;
  const int t = threadIdx.x;

  const float* feat;
  const float* prop;
  int H;
  if (lvl == 0) {
    feat = f3; prop = p3; H = 64;
  } else if (lvl == 1) {
    feat = f4; prop = p4; H = 32;
  } else {
    feat = f5; prop = p5; H = 16;
  }
  const float scale = 1.0f / (float)(8 << lvl);

  // ---- phase 1: axis coefficients -----------------------------------------
  if (t < 2 * G_) {
    const float bx1 = prop[(b * R_ + r) * 4 + 0];
    const float by1 = prop[(b * R_ + r) * 4 + 1];
    const float bx2 = prop[(b * R_ + r) * 4 + 2];
    const float by2 = prop[(b * R_ + r) * 4 + 3];
    const float ax = bx1 * scale - 0.5f;
    const float ay = by1 * scale - 0.5f;
    const float rw = bx2 * scale - 0.5f - ax;
    const float rh = by2 * scale - 0.5f - ay;
    const int i = (t < G_) ? t : (t - G_);
    const float frac = ((float)i + 0.5f) / (float)G_;
    if (t < G_) {
      float yy = ay + frac * rh;
      float v = (yy >= -1.0f && yy <= (float)H) ? 1.0f : 0.0f;
      float y = fminf(fmaxf(yy, 0.0f), (float)(H - 1));
      float y0f = floorf(y);
      int y0 = (int)y0f;
      s_iy0[i] = y0;
      s_iy1[i] = min(y0 + 1, H - 1);
      s_ly[i] = y - y0f;
      s_vy[i] = v;
    } else {
      float xx = ax + frac * rw;
      float v = (xx >= -1.0f && xx <= (float)H) ? 1.0f : 0.0f;
      float x = fminf(fmaxf(xx, 0.0f), (float)(H - 1));
      float x0f = floorf(x);
      int x0 = (int)x0f;
      s_ix0[i] = x0;
      s_ix1[i] = min(x0 + 1, H - 1);
      s_lx[i] = x - x0f;
      s_vx[i] = v;
    }
  }
  __syncthreads();

  // ---- phase 2: roi-align, thread = input channel -------------------------
  {
    const int ci = t;
    const float* fch = feat + (size_t)(b * C_ + ci) * H * H;
    for (int py = 0; py < ROI_; ++py) {
      for (int px = 0; px < ROI_; ++px) {
        float acc = 0.f;
#pragma unroll
        for (int sy = 0; sy < 2; ++sy) {
          const int gy = 2 * py + sy;
          const int iy0 = s_iy0[gy], iy1 = s_iy1[gy];
          const float ly = s_ly[gy], vy = s_vy[gy];
          const float hy = 1.0f - ly;
#pragma unroll
          for (int sx = 0; sx < 2; ++sx) {
            const int gx = 2 * px + sx;
            const int ix0 = s_ix0[gx], ix1 = s_ix1[gx];
            const float lx = s_lx[gx], vx = s_vx[gx];
            const float hx = 1.0f - lx;
            const float f00 = fch[iy0 * H + ix0];
            const float f01 = fch[iy0 * H + ix1];
            const float f10 = fch[iy1 * H + ix0];
            const float f11 = fch[iy1 * H + ix1];
            float v = f00 * (hy * hx) + f01 * (hy * lx) + f10 * (ly * hx) +
                      f11 * (ly * lx);
            acc += (vy * vx) * v;
          }
        }
        s_pool[ci * POOL_LD + py * ROI_ + px] = acc * 0.25f;
      }
    }
  }
  __syncthreads();

  // ---- phase 3: conv3x3 (zero pad), thread = out channel ------------------
  const int co = t;
  float acc[49];
#pragma unroll
  for (int i = 0; i < 49; ++i) acc[i] = 0.f;

  const float* wrow = conv_w + (size_t)co * (C_ * 9);
  float wc[9];
#pragma unroll
  for (int j = 0; j < 9; ++j) wc[j] = wrow[j];

  for (int ci = 0; ci < C_; ++ci) {
    float wn[9];
    if (ci + 1 < C_) {
#pragma unroll
      for (int j = 0; j < 9; ++j) wn[j] = wrow[(ci + 1) * 9 + j];
    }
    const float* prow = &s_pool[ci * POOL_LD];

    // scatter-form conv: input cell (iy,ix) feeds outputs (iy+1-ky, ix+1-kx)
    auto contrib = [&](int cell, float val) {
      const int iy = cell / 7, ix = cell % 7;
#pragma unroll
      for (int ky = 0; ky < 3; ++ky) {
        const int oy = iy + 1 - ky;
        if (oy < 0 || oy > 6) continue;
#pragma unroll
        for (int kx = 0; kx < 3; ++kx) {
          const int ox = ix + 1 - kx;
          if (ox < 0 || ox > 6) continue;
          acc[oy * 7 + ox] = fmaf(wc[ky * 3 + kx], val, acc[oy * 7 + ox]);
        }
      }
    };
#pragma unroll
    for (int jj = 0; jj < 24; ++jj) {
      float2 v2 = *reinterpret_cast<const float2*>(&prow[jj * 2]);
      contrib(jj * 2 + 0, v2.x);
      contrib(jj * 2 + 1, v2.y);
    }
    contrib(48, prow[48]);

    if (ci + 1 < C_) {
#pragma unroll
      for (int j = 0; j < 9; ++j) wc[j] = wn[j];
    }
  }

  // ---- phase 4: relu + FC + reduce ----------------------------------------
  const float cb = conv_b[co];
  float h[49];
#pragma unroll
  for (int i = 0; i < 49; ++i) h[i] = fmaxf(acc[i] + cb, 0.f);

  const int wid = t >> 6;
  for (int k = 0; k < NCLS; ++k) {
    const float* fw = fc_w + (size_t)k * FCK + co * 49;
    float s = 0.f;
#pragma unroll
    for (int p = 0; p < 49; ++p) s = fmaf(fw[p], h[p], s);
#pragma unroll
    for (int off = 32; off > 0; off >>= 1) s += __shfl_down(s, off, 64);
    if ((t & 63) == 0) s_red[k * 4 + wid] = s;
  }
  __syncthreads();
  if (t < NCLS) {
    float v = s_red[t * 4 + 0] + s_red[t * 4 + 1] + s_red[t * 4 + 2] +
              s_red[t * 4 + 3] + fc_b[t];
    out[(size_t)g * NCLS + t] = v;
  }
}

// ---------------------------------------------------------------------------
// Matching: one thread per proposal (3072 total).
// ---------------------------------------------------------------------------
__global__ void match_kernel(const float* __restrict__ p3,
                             const float* __restrict__ p4,
                             const float* __restrict__ p5,
                             const float* __restrict__ gt,
                             float* __restrict__ out) {
  const int g = blockIdx.x * blockDim.x + threadIdx.x;
  if (g >= NROI_TOT) return;
  const int b = g / PROPS_PER_IMG;
  const int i = g - b * PROPS_PER_IMG;
  const int lvl = i >> 8;
  const int r = i & 255;
  const float* prop =
      (lvl == 0 ? p3 : (lvl == 1 ? p4 : p5)) + (size_t)(b * R_ + r) * 4;
  const float px1 = prop[0], py1 = prop[1], px2 = prop[2], py2 = prop[3];
  const float a1 = (px2 - px1) * (py2 - py1);
  const float* gtb = gt + (size_t)b * M_ * 5;

  float best = -2.f;
  int bi = 0;
  for (int j = 0; j < M_; ++j) {
    const float gx1 = gtb[j * 5 + 0], gy1 = gtb[j * 5 + 1];
    const float gx2 = gtb[j * 5 + 2], gy2 = gtb[j * 5 + 3];
    const float cls = gtb[j * 5 + 4];
    const float tlx = fmaxf(px1, gx1), tly = fmaxf(py1, gy1);
    const float brx = fminf(px2, gx2), bry = fminf(py2, gy2);
    const float iw = fmaxf(brx - tlx, 0.f), ih = fmaxf(bry - tly, 0.f);
    const float inter = iw * ih;
    const float a2 = (gx2 - gx1) * (gy2 - gy1);
    const float iou = inter / ((a1 + a2) - inter);
    const float m = (cls != -1.0f) ? iou : -1.0f;
    if (m > best) {  // strict > keeps first-max (jnp.argmax semantics)
      best = m;
      bi = j;
    }
  }
  float o0, o1, o2, o3, o4;
  if (best <= 0.4f) {
    o0 = o1 = o2 = o3 = o4 = -1.0f;          // background
  } else if (best < 0.6f) {
    o0 = o1 = o2 = o3 = o4 = -1e8f;          // neutral
  } else {
    o0 = gtb[bi * 5 + 0]; o1 = gtb[bi * 5 + 1]; o2 = gtb[bi * 5 + 2];
    o3 = gtb[bi * 5 + 3]; o4 = gtb[bi * 5 + 4];
  }
  float* od = out + (size_t)NROI_TOT * NCLS + (size_t)g * 5;
  od[0] = o0; od[1] = o1; od[2] = o2; od[3] = o3; od[4] = o4;
}

extern "C" void kernel_launch(void* const* d_in, const int* in_sizes, int n_in,
                              void* d_out, int out_size, void* d_ws,
                              size_t ws_size, hipStream_t stream) {
  const float* f3 = (const float*)d_in[0];
  const float* f4 = (const float*)d_in[1];
  const float* f5 = (const float*)d_in[2];
  const float* p3 = (const float*)d_in[3];
  const float* p4 = (const float*)d_in[4];
  const float* p5 = (const float*)d_in[5];
  const float* gt = (const float*)d_in[6];
  const float* cw = (const float*)d_in[7];
  const float* cb = (const float*)d_in[8];
  const float* fw = (const float*)d_in[9];
  const float* fb = (const float*)d_in[10];
  float* out = (float*)d_out;

  cls_head_kernel<<<NROI_TOT, 256, 0, stream>>>(f3, f4, f5, p3, p4, p5, cw, cb,
                                                fw, fb, out);
  match_kernel<<<(NROI_TOT + 255) / 256, 256, 0, stream>>>(p3, p4, p5, gt, out);
}

// Round 2
// 2270.068 us; speedup vs baseline: 1.3818x; 1.3818x over previous
//
#include <hip/hip_runtime.h>

typedef unsigned short ushort_t;
typedef __attribute__((ext_vector_type(8))) short short8;
typedef __attribute__((ext_vector_type(16))) float floatx16;

#define B_ 4
#define C_ 256
#define R_ 256
#define M_ 40
#define NCLS 21
#define ROI_ 7
#define G_ 14
#define NROI_TOT 3072
#define PROPS_PER_IMG 768
#define PITCH 264  // pool_t row pitch (ushorts): 528B = 16B-aligned, bank phase 4
#define WCONV_ELEMS (256 * 2304)
#define WFC_ELEMS (21 * 12544)

__device__ __forceinline__ ushort_t f2bf(float f) {
  unsigned u = __builtin_bit_cast(unsigned, f);
  u += 0x7fff + ((u >> 16) & 1);  // RNE
  return (ushort_t)(u >> 16);
}
__device__ __forceinline__ float bf2f(ushort_t h) {
  unsigned u = ((unsigned)h) << 16;
  return __builtin_bit_cast(float, u);
}

// ---------------------------------------------------------------------------
// K0: convert conv_w fp32 [co][ci][3][3] -> bf16 [co][j][ci]  (k = j*256+ci)
//     convert fc_w fp32 -> bf16 flat
// ---------------------------------------------------------------------------
__global__ void prep_kernel(const float* __restrict__ cw,
                            const float* __restrict__ fw,
                            ushort_t* __restrict__ wr,
                            ushort_t* __restrict__ fwb) {
  const int i0 = blockIdx.x * blockDim.x + threadIdx.x;
  const int stride = gridDim.x * blockDim.x;
  for (int idx = i0; idx < WCONV_ELEMS; idx += stride) {
    const int co = idx / 2304;
    const int rem = idx - co * 2304;
    const int j = rem >> 8;
    const int ci = rem & 255;
    wr[idx] = f2bf(cw[(co * 256 + ci) * 9 + j]);
  }
  for (int idx = i0; idx < WFC_ELEMS; idx += stride) fwb[idx] = f2bf(fw[idx]);
}

// ---------------------------------------------------------------------------
// K2: fused roi-align -> bf16 MFMA conv3x3 -> relu -> FC. One block per roi.
// ---------------------------------------------------------------------------
__global__ __launch_bounds__(256, 3) void cls_head_kernel(
    const float* __restrict__ f3, const float* __restrict__ f4,
    const float* __restrict__ f5, const float* __restrict__ p3,
    const float* __restrict__ p4, const float* __restrict__ p5,
    const ushort_t* __restrict__ wr, const float* __restrict__ conv_b,
    const ushort_t* __restrict__ fwb, const float* __restrict__ fc_b,
    float* __restrict__ out) {
  __shared__ ushort_t pool_t[81 * PITCH];  // [padded 9x9 pos][ci], bf16
  __shared__ int s_iy0[G_], s_iy1[G_], s_ix0[G_], s_ix1[G_];
  __shared__ float s_ly[G_], s_lx[G_], s_vy[G_], s_vx[G_];
  __shared__ float s_red[NCLS * 4];

  const int g = blockIdx.x;
  const int b = g / PROPS_PER_IMG;
  const int rem = g - b * PROPS_PER_IMG;
  const int lvl = rem >> 8;
  const int r = rem & 255;
  const int t = threadIdx.x;

  const float* feat;
  const float* prop;
  int H;
  if (lvl == 0) {
    feat = f3; prop = p3; H = 64;
  } else if (lvl == 1) {
    feat = f4; prop = p4; H = 32;
  } else {
    feat = f5; prop = p5; H = 16;
  }
  const float scale = 1.0f / (float)(8 << lvl);

  // ---- zero pool_t (borders must be 0) ------------------------------------
  {
    unsigned* p = (unsigned*)pool_t;
#pragma unroll 4
    for (int i = t; i < 81 * PITCH / 2; i += 256) p[i] = 0u;
  }

  // ---- axis tables --------------------------------------------------------
  if (t < 2 * G_) {
    const float bx1 = prop[(b * R_ + r) * 4 + 0];
    const float by1 = prop[(b * R_ + r) * 4 + 1];
    const float bx2 = prop[(b * R_ + r) * 4 + 2];
    const float by2 = prop[(b * R_ + r) * 4 + 3];
    const float ax = bx1 * scale - 0.5f;
    const float ay = by1 * scale - 0.5f;
    const float rw = bx2 * scale - 0.5f - ax;
    const float rh = by2 * scale - 0.5f - ay;
    const int i = (t < G_) ? t : (t - G_);
    const float frac = ((float)i + 0.5f) / (float)G_;
    if (t < G_) {
      float yy = ay + frac * rh;
      float v = (yy >= -1.0f && yy <= (float)H) ? 1.0f : 0.0f;
      float y = fminf(fmaxf(yy, 0.0f), (float)(H - 1));
      float y0f = floorf(y);
      int y0 = (int)y0f;
      s_iy0[i] = y0;
      s_iy1[i] = min(y0 + 1, H - 1);
      s_ly[i] = y - y0f;
      s_vy[i] = v;
    } else {
      float xx = ax + frac * rw;
      float v = (xx >= -1.0f && xx <= (float)H) ? 1.0f : 0.0f;
      float x = fminf(fmaxf(xx, 0.0f), (float)(H - 1));
      float x0f = floorf(x);
      int x0 = (int)x0f;
      s_ix0[i] = x0;
      s_ix1[i] = min(x0 + 1, H - 1);
      s_lx[i] = x - x0f;
      s_vx[i] = v;
    }
  }
  __syncthreads();

  // ---- roi-align, thread = input channel; write transposed bf16 -----------
  {
    const int ci = t;
    const float* fch = feat + (size_t)(b * C_ + ci) * H * H;
    for (int py = 0; py < ROI_; ++py) {
      for (int px = 0; px < ROI_; ++px) {
        float acc = 0.f;
#pragma unroll
        for (int sy = 0; sy < 2; ++sy) {
          const int gy = 2 * py + sy;
          const int iy0 = s_iy0[gy], iy1 = s_iy1[gy];
          const float ly = s_ly[gy], vy = s_vy[gy];
          const float hy = 1.0f - ly;
#pragma unroll
          for (int sx = 0; sx < 2; ++sx) {
            const int gx = 2 * px + sx;
            const int ix0 = s_ix0[gx], ix1 = s_ix1[gx];
            const float lx = s_lx[gx], vx = s_vx[gx];
            const float hx = 1.0f - lx;
            const float f00 = fch[iy0 * H + ix0];
            const float f01 = fch[iy0 * H + ix1];
            const float f10 = fch[iy1 * H + ix0];
            const float f11 = fch[iy1 * H + ix1];
            float v = f00 * (hy * hx) + f01 * (hy * lx) + f10 * (ly * hx) +
                      f11 * (ly * lx);
            acc += (vy * vx) * v;
          }
        }
        pool_t[((py + 1) * 9 + (px + 1)) * PITCH + ci] = f2bf(acc * 0.25f);
      }
    }
  }
  __syncthreads();

  // ---- MFMA conv: per wave 64 co x 64 pos (49 valid), K = 9*256 -----------
  const int l = t & 63;
  const int w = t >> 6;
  const int ml = l & 31;
  const int quad = l >> 5;  // 0/1
  const int co_base = w * 64;

  const int n0 = ml;        // pos tile 0 (always valid: 0..31)
  const int n1 = ml + 32;   // pos tile 1 (valid if < 49)
  const int bn0 = n0 + 2 * (n0 / 7);
  const int bn1 = (n1 < 49) ? (n1 + 2 * (n1 / 7)) : 0;

  floatx16 acc00, acc01, acc10, acc11;
#pragma unroll
  for (int i = 0; i < 16; ++i) {
    acc00[i] = 0.f; acc01[i] = 0.f; acc10[i] = 0.f; acc11[i] = 0.f;
  }

  const ushort_t* ap0 = wr + (size_t)(co_base + ml) * 2304 + quad * 8;
  const ushort_t* ap1 = ap0 + 32 * 2304;

  for (int j = 0; j < 9; ++j) {
    const int off = (j / 3) * 9 + (j % 3);  // ky*9+kx
    const ushort_t* bp0 = &pool_t[(bn0 + off) * PITCH + quad * 8];
    const ushort_t* bp1 = &pool_t[(bn1 + off) * PITCH + quad * 8];
    const ushort_t* aj0 = ap0 + j * 256;
    const ushort_t* aj1 = ap1 + j * 256;
#pragma unroll
    for (int ks = 0; ks < 16; ++ks) {
      short8 b0 = *(const short8*)(bp0 + ks * 16);
      short8 b1 = *(const short8*)(bp1 + ks * 16);
      short8 a0 = *(const short8*)(aj0 + ks * 16);
      short8 a1 = *(const short8*)(aj1 + ks * 16);
      acc00 = __builtin_amdgcn_mfma_f32_32x32x16_bf16(a0, b0, acc00, 0, 0, 0);
      acc01 = __builtin_amdgcn_mfma_f32_32x32x16_bf16(a0, b1, acc01, 0, 0, 0);
      acc10 = __builtin_amdgcn_mfma_f32_32x32x16_bf16(a1, b0, acc10, 0, 0, 0);
      acc11 = __builtin_amdgcn_mfma_f32_32x32x16_bf16(a1, b1, acc11, 0, 0, 0);
    }
  }

  // ---- epilogue: bias + relu (C/D layout: col=lane&31, row=(reg&3)+8*(reg>>2)+4*quad)
  const float val1 = (n1 < 49) ? 1.f : 0.f;
#pragma unroll
  for (int reg = 0; reg < 16; ++reg) {
    const int dco = (reg & 3) + 8 * (reg >> 2) + 4 * quad;
    const float b0v = conv_b[co_base + dco];
    const float b1v = conv_b[co_base + 32 + dco];
    acc00[reg] = fmaxf(acc00[reg] + b0v, 0.f);
    acc10[reg] = fmaxf(acc10[reg] + b1v, 0.f);
    acc01[reg] = val1 * fmaxf(acc01[reg] + b0v, 0.f);
    acc11[reg] = val1 * fmaxf(acc11[reg] + b1v, 0.f);
  }

  // ---- FC(12544 -> 21): per-lane partial over (64 co x my pos), reduce ----
  const int pos0 = n0;
  const int pos1c = (n1 < 49) ? n1 : 0;  // clamped; h already zeroed
  for (int k = 0; k < NCLS; ++k) {
    const ushort_t* fp = fwb + (size_t)k * 12544 + (co_base + 4 * quad) * 49;
    const ushort_t* fp0a = fp + pos0;
    const ushort_t* fp1a = fp + pos1c;
    const ushort_t* fp0b = fp + 32 * 49 + pos0;
    const ushort_t* fp1b = fp + 32 * 49 + pos1c;
    float s = 0.f;
#pragma unroll
    for (int reg = 0; reg < 16; ++reg) {
      const int o = ((reg & 3) + 8 * (reg >> 2)) * 49;
      s += bf2f(fp0a[o]) * acc00[reg];
      s += bf2f(fp1a[o]) * acc01[reg];
      s += bf2f(fp0b[o]) * acc10[reg];
      s += bf2f(fp1b[o]) * acc11[reg];
    }
#pragma unroll
    for (int off = 32; off > 0; off >>= 1) s += __shfl_down(s, off, 64);
    if (l == 0) s_red[k * 4 + w] = s;
  }
  __syncthreads();
  if (t < NCLS) {
    float v = s_red[t * 4 + 0] + s_red[t * 4 + 1] + s_red[t * 4 + 2] +
              s_red[t * 4 + 3] + fc_b[t];
    out[(size_t)g * NCLS + t] = v;
  }
}

// ---------------------------------------------------------------------------
// Matching: one thread per proposal.
// ---------------------------------------------------------------------------
__global__ void match_kernel(const float* __restrict__ p3,
                             const float* __restrict__ p4,
                             const float* __restrict__ p5,
                             const float* __restrict__ gt,
                             float* __restrict__ out) {
  const int g = blockIdx.x * blockDim.x + threadIdx.x;
  if (g >= NROI_TOT) return;
  const int b = g / PROPS_PER_IMG;
  const int i = g - b * PROPS_PER_IMG;
  const int lvl = i >> 8;
  const int r = i & 255;
  const float* prop =
      (lvl == 0 ? p3 : (lvl == 1 ? p4 : p5)) + (size_t)(b * R_ + r) * 4;
  const float px1 = prop[0], py1 = prop[1], px2 = prop[2], py2 = prop[3];
  const float a1 = (px2 - px1) * (py2 - py1);
  const float* gtb = gt + (size_t)b * M_ * 5;

  float best = -2.f;
  int bi = 0;
  for (int j = 0; j < M_; ++j) {
    const float gx1 = gtb[j * 5 + 0], gy1 = gtb[j * 5 + 1];
    const float gx2 = gtb[j * 5 + 2], gy2 = gtb[j * 5 + 3];
    const float cls = gtb[j * 5 + 4];
    const float tlx = fmaxf(px1, gx1), tly = fmaxf(py1, gy1);
    const float brx = fminf(px2, gx2), bry = fminf(py2, gy2);
    const float iw = fmaxf(brx - tlx, 0.f), ih = fmaxf(bry - tly, 0.f);
    const float inter = iw * ih;
    const float a2 = (gx2 - gx1) * (gy2 - gy1);
    const float iou = inter / ((a1 + a2) - inter);
    const float m = (cls != -1.0f) ? iou : -1.0f;
    if (m > best) { best = m; bi = j; }
  }
  float o0, o1, o2, o3, o4;
  if (best <= 0.4f) {
    o0 = o1 = o2 = o3 = o4 = -1.0f;
  } else if (best < 0.6f) {
    o0 = o1 = o2 = o3 = o4 = -1e8f;
  } else {
    o0 = gtb[bi * 5 + 0]; o1 = gtb[bi * 5 + 1]; o2 = gtb[bi * 5 + 2];
    o3 = gtb[bi * 5 + 3]; o4 = gtb[bi * 5 + 4];
  }
  float* od = out + (size_t)NROI_TOT * NCLS + (size_t)g * 5;
  od[0] = o0; od[1] = o1; od[2] = o2; od[3] = o3; od[4] = o4;
}

extern "C" void kernel_launch(void* const* d_in, const int* in_sizes, int n_in,
                              void* d_out, int out_size, void* d_ws,
                              size_t ws_size, hipStream_t stream) {
  const float* f3 = (const float*)d_in[0];
  const float* f4 = (const float*)d_in[1];
  const float* f5 = (const float*)d_in[2];
  const float* p3 = (const float*)d_in[3];
  const float* p4 = (const float*)d_in[4];
  const float* p5 = (const float*)d_in[5];
  const float* gt = (const float*)d_in[6];
  const float* cw = (const float*)d_in[7];
  const float* cb = (const float*)d_in[8];
  const float* fw = (const float*)d_in[9];
  const float* fb = (const float*)d_in[10];
  float* out = (float*)d_out;

  ushort_t* wr = (ushort_t*)d_ws;                      // 1,179,648 B
  ushort_t* fwb = wr + WCONV_ELEMS;                    // 526,848 B

  prep_kernel<<<512, 256, 0, stream>>>(cw, fw, wr, fwb);
  cls_head_kernel<<<NROI_TOT, 256, 0, stream>>>(f3, f4, f5, p3, p4, p5, wr, cb,
                                                fwb, fb, out);
  match_kernel<<<(NROI_TOT + 255) / 256, 256, 0, stream>>>(p3, p4, p5, gt, out);
}

// Round 3
// 1783.735 us; speedup vs baseline: 1.7586x; 1.2726x over previous
//
#include <hip/hip_runtime.h>

typedef unsigned short ushort_t;
typedef __attribute__((ext_vector_type(8))) short short8;
typedef __attribute__((ext_vector_type(16))) float floatx16;

#define B_ 4
#define C_ 256
#define R_ 256
#define M_ 40
#define NCLS 21
#define ROI_ 7
#define G_ 14
#define NROI_TOT 3072
#define PROPS_PER_IMG 768
#define POOL_PITCH 264   // ushorts per pool row (528 B, 16B-aligned)
#define CHUNK_PITCH 24   // ushorts per chunk row (48 B, 16B-aligned)
#define WCONV_ELEMS (256 * 2304)
#define WFC_ELEMS (21 * 12544)

__device__ __forceinline__ ushort_t f2bf(float f) {
  unsigned u = __builtin_bit_cast(unsigned, f);
  u += 0x7fff + ((u >> 16) & 1);  // RNE
  return (ushort_t)(u >> 16);
}
__device__ __forceinline__ float bf2f(ushort_t h) {
  unsigned u = ((unsigned)h) << 16;
  return __builtin_bit_cast(float, u);
}

// ---------------------------------------------------------------------------
// K0: conv_w fp32 [co][ci][3][3] -> bf16 [co][j][ci] (k = j*256+ci);
//     fc_w fp32 -> bf16 flat.
// ---------------------------------------------------------------------------
__global__ void prep_kernel(const float* __restrict__ cw,
                            const float* __restrict__ fw,
                            ushort_t* __restrict__ wr,
                            ushort_t* __restrict__ fwb) {
  const int i0 = blockIdx.x * blockDim.x + threadIdx.x;
  const int stride = gridDim.x * blockDim.x;
  for (int idx = i0; idx < WCONV_ELEMS; idx += stride) {
    const int co = idx / 2304;
    const int rem = idx - co * 2304;
    const int j = rem >> 8;
    const int ci = rem & 255;
    wr[idx] = f2bf(cw[(co * 256 + ci) * 9 + j]);
  }
  for (int idx = i0; idx < WFC_ELEMS; idx += stride) fwb[idx] = f2bf(fw[idx]);
}

__device__ __forceinline__ void decode_roi(int gid, const float* p3,
                                           const float* p4, const float* p5,
                                           const float* f3, const float* f4,
                                           const float* f5, const float*& prop,
                                           const float*& feat, int& b, int& H,
                                           float& scale) {
  b = gid / PROPS_PER_IMG;
  const int rem = gid - b * PROPS_PER_IMG;
  const int lvl = rem >> 8;
  const int r = rem & 255;
  if (lvl == 0) { feat = f3; prop = p3; H = 64; }
  else if (lvl == 1) { feat = f4; prop = p4; H = 32; }
  else { feat = f5; prop = p5; H = 16; }
  scale = 1.0f / (float)(8 << lvl);
  prop += (size_t)(b * R_ + r) * 4;
}

// ---------------------------------------------------------------------------
// K1: fused roi-align -> LDS-staged bf16 MFMA conv3x3 -> relu -> FC.
//     One block = 256 threads (4 waves) handles 2 rois.
//     Wave w: co tile [64w, 64w+64) x all 128 pos (2 rois x 64, 49 valid).
// ---------------------------------------------------------------------------
__global__ __launch_bounds__(256, 2) void cls_head_kernel(
    const float* __restrict__ f3, const float* __restrict__ f4,
    const float* __restrict__ f5, const float* __restrict__ p3,
    const float* __restrict__ p4, const float* __restrict__ p5,
    const ushort_t* __restrict__ wr, const float* __restrict__ conv_b,
    const ushort_t* __restrict__ fwb, const float* __restrict__ fc_b,
    float* __restrict__ out) {
  __shared__ __align__(16) ushort_t s_pool[2 * 50 * POOL_PITCH];  // 52.8 KB
  __shared__ __align__(16) ushort_t s_chunk[256 * CHUNK_PITCH];   // 12.3 KB
  __shared__ int s_iy0[28], s_iy1[28], s_ix0[28], s_ix1[28];
  __shared__ float s_ly[28], s_lx[28], s_vy[28], s_vx[28];

  const int g = blockIdx.x;
  const int t = threadIdx.x;

  // prologue staging load for chunk 0 (j=0, kc=0): thread t = co row, 32 B
  const ushort_t* wbase = wr + (size_t)t * 2304;
  short8 r0 = *(const short8*)(wbase);
  short8 r1 = *(const short8*)(wbase + 8);

  // zero rows 49 (im2col zero-row per roi)
  if (t < POOL_PITCH) {
    s_pool[49 * POOL_PITCH + t] = 0;
    s_pool[99 * POOL_PITCH + t] = 0;
  }

  // ---- axis tables for both rois ------------------------------------------
  if (t < 56) {
    const int rr = t / 28;
    const int tt = t - rr * 28;
    const float *prop, *feat;
    int b, H;
    float scale;
    decode_roi(g * 2 + rr, p3, p4, p5, f3, f4, f5, prop, feat, b, H, scale);
    const float bx1 = prop[0], by1 = prop[1], bx2 = prop[2], by2 = prop[3];
    const float ax = bx1 * scale - 0.5f;
    const float ay = by1 * scale - 0.5f;
    const float rw = bx2 * scale - 0.5f - ax;
    const float rh = by2 * scale - 0.5f - ay;
    const int i = (tt < G_) ? tt : (tt - G_);
    const float frac = ((float)i + 0.5f) / (float)G_;
    const int o = rr * G_ + i;
    if (tt < G_) {
      float yy = ay + frac * rh;
      float v = (yy >= -1.0f && yy <= (float)H) ? 1.0f : 0.0f;
      float y = fminf(fmaxf(yy, 0.0f), (float)(H - 1));
      float y0f = floorf(y);
      int y0 = (int)y0f;
      s_iy0[o] = y0;
      s_iy1[o] = min(y0 + 1, H - 1);
      s_ly[o] = y - y0f;
      s_vy[o] = v;
    } else {
      float xx = ax + frac * rw;
      float v = (xx >= -1.0f && xx <= (float)H) ? 1.0f : 0.0f;
      float x = fminf(fmaxf(xx, 0.0f), (float)(H - 1));
      float x0f = floorf(x);
      int x0 = (int)x0f;
      s_ix0[o] = x0;
      s_ix1[o] = min(x0 + 1, H - 1);
      s_lx[o] = x - x0f;
      s_vx[o] = v;
    }
  }
  __syncthreads();

  // ---- roi-align: thread = channel, both rois -----------------------------
  for (int rr = 0; rr < 2; ++rr) {
    const float *prop, *feat;
    int b, H;
    float scale;
    decode_roi(g * 2 + rr, p3, p4, p5, f3, f4, f5, prop, feat, b, H, scale);
    const float* fch = feat + (size_t)(b * C_ + t) * H * H;
    ushort_t* pdst = &s_pool[rr * 50 * POOL_PITCH + t];
    for (int py = 0; py < ROI_; ++py) {
      for (int px = 0; px < ROI_; ++px) {
        float acc = 0.f;
#pragma unroll
        for (int sy = 0; sy < 2; ++sy) {
          const int gy = rr * G_ + 2 * py + sy;
          const int iy0 = s_iy0[gy], iy1 = s_iy1[gy];
          const float ly = s_ly[gy], vy = s_vy[gy];
          const float hy = 1.0f - ly;
#pragma unroll
          for (int sx = 0; sx < 2; ++sx) {
            const int gx = rr * G_ + 2 * px + sx;
            const int ix0 = s_ix0[gx], ix1 = s_ix1[gx];
            const float lx = s_lx[gx], vx = s_vx[gx];
            const float hx = 1.0f - lx;
            const float f00 = fch[iy0 * H + ix0];
            const float f01 = fch[iy0 * H + ix1];
            const float f10 = fch[iy1 * H + ix0];
            const float f11 = fch[iy1 * H + ix1];
            float v = f00 * (hy * hx) + f01 * (hy * lx) + f10 * (ly * hx) +
                      f11 * (ly * lx);
            acc += (vy * vx) * v;
          }
        }
        pdst[(py * ROI_ + px) * POOL_PITCH] = f2bf(acc * 0.25f);
      }
    }
  }
  // (visibility guaranteed by first barrier inside the K-loop)

  // ---- MFMA conv ----------------------------------------------------------
  const int l = t & 63;
  const int w = t >> 6;
  const int ml = l & 31;
  const int quad = l >> 5;
  const int co_base = w * 64;

  const int pA = ml;       // pos tiles ns=0 (roi0), ns=2 (roi1)
  const int pB = ml + 32;  // pos tiles ns=1 (roi0), ns=3 (roi1); valid < 49
  const int pyA = pA / 7, pxA = pA % 7;
  const int pyB = pB / 7, pxB = pB % 7;

  floatx16 acc[8];
#pragma unroll
  for (int a = 0; a < 8; ++a)
#pragma unroll
    for (int i = 0; i < 16; ++i) acc[a][i] = 0.f;

  int kk_next = 1;
  for (int j = 0; j < 9; ++j) {
    const int dy = j / 3 - 1, dx = j % 3 - 1;
    int bnA, bnB;
    {
      const int ry = pyA + dy, rx = pxA + dx;
      const bool ok = (ry >= 0) & (ry < 7) & (rx >= 0) & (rx < 7);
      bnA = ok ? ry * 7 + rx : 49;
    }
    {
      const int ry = pyB + dy, rx = pxB + dx;
      const bool ok = (pB < 49) & (ry >= 0) & (ry < 7) & (rx >= 0) & (rx < 7);
      bnB = ok ? ry * 7 + rx : 49;
    }
    const int row0 = bnA, row1 = bnB, row2 = 50 + bnA, row3 = 50 + bnB;

    for (int kc = 0; kc < 16; ++kc) {
      __syncthreads();  // previous chunk fully consumed (or pool ready)
      *(short8*)&s_chunk[t * CHUNK_PITCH] = r0;
      *(short8*)&s_chunk[t * CHUNK_PITCH + 8] = r1;
      __syncthreads();
      if (kk_next < 144) {
        const int nj = kk_next >> 4, nkc = kk_next & 15;
        const ushort_t* np = wbase + nj * 256 + nkc * 16;
        r0 = *(const short8*)(np);
        r1 = *(const short8*)(np + 8);
        ++kk_next;
      }
      const short8 a0 =
          *(const short8*)&s_chunk[(co_base + ml) * CHUNK_PITCH + quad * 8];
      const short8 a1 = *(
          const short8*)&s_chunk[(co_base + 32 + ml) * CHUNK_PITCH + quad * 8];
      const int cof = kc * 16 + quad * 8;
      const short8 b0 = *(const short8*)&s_pool[row0 * POOL_PITCH + cof];
      const short8 b1 = *(const short8*)&s_pool[row1 * POOL_PITCH + cof];
      const short8 b2 = *(const short8*)&s_pool[row2 * POOL_PITCH + cof];
      const short8 b3 = *(const short8*)&s_pool[row3 * POOL_PITCH + cof];
      acc[0] = __builtin_amdgcn_mfma_f32_32x32x16_bf16(a0, b0, acc[0], 0, 0, 0);
      acc[1] = __builtin_amdgcn_mfma_f32_32x32x16_bf16(a0, b1, acc[1], 0, 0, 0);
      acc[2] = __builtin_amdgcn_mfma_f32_32x32x16_bf16(a0, b2, acc[2], 0, 0, 0);
      acc[3] = __builtin_amdgcn_mfma_f32_32x32x16_bf16(a0, b3, acc[3], 0, 0, 0);
      acc[4] = __builtin_amdgcn_mfma_f32_32x32x16_bf16(a1, b0, acc[4], 0, 0, 0);
      acc[5] = __builtin_amdgcn_mfma_f32_32x32x16_bf16(a1, b1, acc[5], 0, 0, 0);
      acc[6] = __builtin_amdgcn_mfma_f32_32x32x16_bf16(a1, b2, acc[6], 0, 0, 0);
      acc[7] = __builtin_amdgcn_mfma_f32_32x32x16_bf16(a1, b3, acc[7], 0, 0, 0);
    }
  }
  __syncthreads();  // all pool reads done before h overwrites it

  // ---- epilogue: bias + relu -> h in LDS (fc-k order: [rr][co*49+pos]) ----
  ushort_t* h_lds = s_pool;  // 2*12544 ushorts fit in pool area
#pragma unroll
  for (int cs = 0; cs < 2; ++cs) {
#pragma unroll
    for (int reg = 0; reg < 16; ++reg) {
      const int co = co_base + cs * 32 + (reg & 3) + 8 * (reg >> 2) + 4 * quad;
      const float cb = conv_b[co];
      const int base = co * 49;
      h_lds[base + pA] = f2bf(fmaxf(acc[cs * 4 + 0][reg] + cb, 0.f));
      h_lds[12544 + base + pA] = f2bf(fmaxf(acc[cs * 4 + 2][reg] + cb, 0.f));
      if (pB < 49) {
        h_lds[base + pB] = f2bf(fmaxf(acc[cs * 4 + 1][reg] + cb, 0.f));
        h_lds[12544 + base + pB] = f2bf(fmaxf(acc[cs * 4 + 3][reg] + cb, 0.f));
      }
    }
  }
  __syncthreads();

  // ---- FC(12544 -> 21) per roi: wave-parallel over (roi, class) tasks -----
  for (int task = w; task < 2 * NCLS; task += 4) {
    const int rr = task / NCLS;
    const int c = task - rr * NCLS;
    const ushort_t* fr = fwb + (size_t)c * 12544;
    const ushort_t* hr = h_lds + rr * 12544;
    float s = 0.f;
    for (int it = 0; it < 25; ++it) {
      const int slot = it * 64 + l;
      if (slot < 1568) {
        const short8 wv = *(const short8*)(fr + slot * 8);
        const short8 hv = *(const short8*)(hr + slot * 8);
#pragma unroll
        for (int i = 0; i < 8; ++i)
          s += bf2f((ushort_t)wv[i]) * bf2f((ushort_t)hv[i]);
      }
    }
#pragma unroll
    for (int off = 32; off > 0; off >>= 1) s += __shfl_down(s, off, 64);
    if (l == 0) out[(size_t)(g * 2 + rr) * NCLS + c] = s + fc_b[c];
  }
}

// ---------------------------------------------------------------------------
// Matching: one thread per proposal.
// ---------------------------------------------------------------------------
__global__ void match_kernel(const float* __restrict__ p3,
                             const float* __restrict__ p4,
                             const float* __restrict__ p5,
                             const float* __restrict__ gt,
                             float* __restrict__ out) {
  const int g = blockIdx.x * blockDim.x + threadIdx.x;
  if (g >= NROI_TOT) return;
  const int b = g / PROPS_PER_IMG;
  const int i = g - b * PROPS_PER_IMG;
  const int lvl = i >> 8;
  const int r = i & 255;
  const float* prop =
      (lvl == 0 ? p3 : (lvl == 1 ? p4 : p5)) + (size_t)(b * R_ + r) * 4;
  const float px1 = prop[0], py1 = prop[1], px2 = prop[2], py2 = prop[3];
  const float a1 = (px2 - px1) * (py2 - py1);
  const float* gtb = gt + (size_t)b * M_ * 5;

  float best = -2.f;
  int bi = 0;
  for (int j = 0; j < M_; ++j) {
    const float gx1 = gtb[j * 5 + 0], gy1 = gtb[j * 5 + 1];
    const float gx2 = gtb[j * 5 + 2], gy2 = gtb[j * 5 + 3];
    const float cls = gtb[j * 5 + 4];
    const float tlx = fmaxf(px1, gx1), tly = fmaxf(py1, gy1);
    const float brx = fminf(px2, gx2), bry = fminf(py2, gy2);
    const float iw = fmaxf(brx - tlx, 0.f), ih = fmaxf(bry - tly, 0.f);
    const float inter = iw * ih;
    const float a2 = (gx2 - gx1) * (gy2 - gy1);
    const float iou = inter / ((a1 + a2) - inter);
    const float m = (cls != -1.0f) ? iou : -1.0f;
    if (m > best) { best = m; bi = j; }
  }
  float o0, o1, o2, o3, o4;
  if (best <= 0.4f) {
    o0 = o1 = o2 = o3 = o4 = -1.0f;
  } else if (best < 0.6f) {
    o0 = o1 = o2 = o3 = o4 = -1e8f;
  } else {
    o0 = gtb[bi * 5 + 0]; o1 = gtb[bi * 5 + 1]; o2 = gtb[bi * 5 + 2];
    o3 = gtb[bi * 5 + 3]; o4 = gtb[bi * 5 + 4];
  }
  float* od = out + (size_t)NROI_TOT * NCLS + (size_t)g * 5;
  od[0] = o0; od[1] = o1; od[2] = o2; od[3] = o3; od[4] = o4;
}

extern "C" void kernel_launch(void* const* d_in, const int* in_sizes, int n_in,
                              void* d_out, int out_size, void* d_ws,
                              size_t ws_size, hipStream_t stream) {
  const float* f3 = (const float*)d_in[0];
  const float* f4 = (const float*)d_in[1];
  const float* f5 = (const float*)d_in[2];
  const float* p3 = (const float*)d_in[3];
  const float* p4 = (const float*)d_in[4];
  const float* p5 = (const float*)d_in[5];
  const float* gt = (const float*)d_in[6];
  const float* cw = (const float*)d_in[7];
  const float* cb = (const float*)d_in[8];
  const float* fw = (const float*)d_in[9];
  const float* fb = (const float*)d_in[10];
  float* out = (float*)d_out;

  ushort_t* wr = (ushort_t*)d_ws;            // 1,179,648 B
  ushort_t* fwb = wr + WCONV_ELEMS;          // 526,848 B

  prep_kernel<<<512, 256, 0, stream>>>(cw, fw, wr, fwb);
  cls_head_kernel<<<NROI_TOT / 2, 256, 0, stream>>>(f3, f4, f5, p3, p4, p5, wr,
                                                    cb, fwb, fb, out);
  match_kernel<<<(NROI_TOT + 255) / 256, 256, 0, stream>>>(p3, p4, p5, gt, out);
}

// Round 4
// 560.487 us; speedup vs baseline: 5.5967x; 3.1825x over previous
//
#include <hip/hip_runtime.h>

typedef unsigned short ushort_t;
typedef __attribute__((ext_vector_type(4))) unsigned short ushort4_t;
typedef __attribute__((ext_vector_type(8))) short short8;
typedef __attribute__((ext_vector_type(16))) float floatx16;

#define B_ 4
#define C_ 256
#define R_ 256
#define M_ 40
#define NCLS 21
#define ROI_ 7
#define G_ 14
#define NROI_TOT 3072
#define PROPS_PER_IMG 768
#define POOL_PITCH 264   // ushorts per pool row (528 B, 16B-aligned)
#define CHUNK_PITCH 24   // ushorts per chunk row (48 B, 16B-aligned)
#define WCONV_ELEMS (256 * 2304)
#define WFC_ELEMS (21 * 12544)
// ws layout (ushort offsets)
#define OFF_FWB   WCONV_ELEMS
#define OFF_CL3   (OFF_FWB + WFC_ELEMS)                // 4*64*64*256
#define OFF_CL4   (OFF_CL3 + 4 * 64 * 64 * 256)        // 4*32*32*256
#define OFF_CL5   (OFF_CL4 + 4 * 32 * 32 * 256)        // 4*16*16*256

__device__ __forceinline__ ushort_t f2bf(float f) {
  unsigned u = __builtin_bit_cast(unsigned, f);
  u += 0x7fff + ((u >> 16) & 1);  // RNE
  return (ushort_t)(u >> 16);
}
__device__ __forceinline__ float bf2f(ushort_t h) {
  unsigned u = ((unsigned)h) << 16;
  return __builtin_bit_cast(float, u);
}

// ---------------------------------------------------------------------------
// K0a: conv_w fp32 [co][ci][3][3] -> bf16 [co][j][ci]; fc_w -> bf16 flat.
// ---------------------------------------------------------------------------
__global__ void prep_w_kernel(const float* __restrict__ cw,
                              const float* __restrict__ fw,
                              ushort_t* __restrict__ wr,
                              ushort_t* __restrict__ fwb) {
  const int i0 = blockIdx.x * blockDim.x + threadIdx.x;
  const int stride = gridDim.x * blockDim.x;
  for (int idx = i0; idx < WCONV_ELEMS; idx += stride) {
    const int co = idx / 2304;
    const int rem = idx - co * 2304;
    const int j = rem >> 8;
    const int ci = rem & 255;
    wr[idx] = f2bf(cw[(co * 256 + ci) * 9 + j]);
  }
  for (int idx = i0; idx < WFC_ELEMS; idx += stride) fwb[idx] = f2bf(fw[idx]);
}

// ---------------------------------------------------------------------------
// K0b: feats fp32 [b][c][y][x] -> channels-last bf16 [b][y][x][c].
// One block per (lvl, b, y); LDS tile transpose, coalesced both sides.
// ---------------------------------------------------------------------------
__global__ __launch_bounds__(256) void prep_feats_kernel(
    const float* __restrict__ f3, const float* __restrict__ f4,
    const float* __restrict__ f5, ushort_t* __restrict__ cl3,
    ushort_t* __restrict__ cl4, ushort_t* __restrict__ cl5) {
  __shared__ ushort_t tile[64 * 257];
  const int id = blockIdx.x;
  const int t = threadIdx.x;
  const float* in;
  ushort_t* outp;
  int b, y, W;
  if (id < 256) { in = f3; outp = cl3; W = 64; b = id >> 6; y = id & 63; }
  else if (id < 384) { in = f4; outp = cl4; W = 32; b = (id - 256) >> 5; y = (id - 256) & 31; }
  else { in = f5; outp = cl5; W = 16; b = (id - 384) >> 4; y = (id - 384) & 15; }

  // load: lane->x (coalesced fp32), write LDS [x][c]
  for (int idx = t; idx < 256 * W; idx += 256) {
    const int c = idx / W;
    const int x = idx - c * W;
    tile[x * 257 + c] = f2bf(in[((size_t)(b * 256 + c) * W + y) * W + x]);
  }
  __syncthreads();
  // store: lane->c4 (coalesced ushort4)
  ushort_t* orow = outp + ((size_t)(b * W + y) * W) * 256;
  for (int idx = t; idx < W * 64; idx += 256) {
    const int x = idx >> 6;
    const int c4 = (idx & 63) * 4;
    ushort4_t v;
    v[0] = tile[x * 257 + c4 + 0];
    v[1] = tile[x * 257 + c4 + 1];
    v[2] = tile[x * 257 + c4 + 2];
    v[3] = tile[x * 257 + c4 + 3];
    *(ushort4_t*)(orow + (size_t)x * 256 + c4) = v;
  }
}

// ---------------------------------------------------------------------------
// K1: fused roi-align (channels-last) -> LDS-staged bf16 MFMA conv3x3 ->
//     relu -> FC. One block (4 waves) per 2 rois.
// ---------------------------------------------------------------------------
__global__ __launch_bounds__(256, 2) void cls_head_kernel(
    const ushort_t* __restrict__ cl3, const ushort_t* __restrict__ cl4,
    const ushort_t* __restrict__ cl5, const float* __restrict__ p3,
    const float* __restrict__ p4, const float* __restrict__ p5,
    const ushort_t* __restrict__ wr, const float* __restrict__ conv_b,
    const ushort_t* __restrict__ fwb, const float* __restrict__ fc_b,
    float* __restrict__ out) {
  __shared__ __align__(16) ushort_t s_pool[2 * 50 * POOL_PITCH];  // 52.8 KB
  __shared__ __align__(16) ushort_t s_chunk[256 * CHUNK_PITCH];   // 12.3 KB
  __shared__ int s_iy0[28], s_iy1[28], s_ix0[28], s_ix1[28];
  __shared__ float s_ly[28], s_lx[28], s_vy[28], s_vx[28];

  const int g = blockIdx.x;
  const int t = threadIdx.x;

  // weight prefetch pipeline, depth 2 (chunks 0 and 1)
  const ushort_t* wbase = wr + (size_t)t * 2304;
  short8 cur0 = *(const short8*)(wbase);
  short8 cur1 = *(const short8*)(wbase + 8);
  short8 nxt0 = *(const short8*)(wbase + 16);
  short8 nxt1 = *(const short8*)(wbase + 24);

  // per-roi metadata
  const ushort_t* clb_[2];
  int W_[2];
  const float* prop_[2];
#pragma unroll
  for (int rr = 0; rr < 2; ++rr) {
    const int rid = g * 2 + rr;
    const int b = rid / PROPS_PER_IMG;
    const int rem = rid - b * PROPS_PER_IMG;
    const int lvl = rem >> 8;
    const int r = rem & 255;
    const ushort_t* base;
    const float* pp;
    int Wl;
    if (lvl == 0) { base = cl3; pp = p3; Wl = 64; }
    else if (lvl == 1) { base = cl4; pp = p4; Wl = 32; }
    else { base = cl5; pp = p5; Wl = 16; }
    clb_[rr] = base + (size_t)b * Wl * Wl * 256;
    W_[rr] = Wl;
    prop_[rr] = pp + (size_t)(b * R_ + r) * 4;
  }

  // zero rows 49/99 (im2col zero-row per roi); cols 0..255 suffice
  s_pool[49 * POOL_PITCH + t] = 0;
  s_pool[99 * POOL_PITCH + t] = 0;

  // ---- axis tables for both rois ------------------------------------------
  if (t < 56) {
    const int rr = t / 28;
    const int tt = t - rr * 28;
    const float* prop = prop_[rr];
    const int H = W_[rr];
    const float scale = 1.0f / (float)(H == 64 ? 8 : (H == 32 ? 16 : 32));
    const float bx1 = prop[0], by1 = prop[1], bx2 = prop[2], by2 = prop[3];
    const float ax = bx1 * scale - 0.5f;
    const float ay = by1 * scale - 0.5f;
    const float rw = bx2 * scale - 0.5f - ax;
    const float rh = by2 * scale - 0.5f - ay;
    const int i = (tt < G_) ? tt : (tt - G_);
    const float frac = ((float)i + 0.5f) / (float)G_;
    const int o = rr * G_ + i;
    if (tt < G_) {
      float yy = ay + frac * rh;
      float v = (yy >= -1.0f && yy <= (float)H) ? 1.0f : 0.0f;
      float y = fminf(fmaxf(yy, 0.0f), (float)(H - 1));
      float y0f = floorf(y);
      int y0 = (int)y0f;
      s_iy0[o] = y0;
      s_iy1[o] = min(y0 + 1, H - 1);
      s_ly[o] = y - y0f;
      s_vy[o] = v;
    } else {
      float xx = ax + frac * rw;
      float v = (xx >= -1.0f && xx <= (float)H) ? 1.0f : 0.0f;
      float x = fminf(fmaxf(xx, 0.0f), (float)(H - 1));
      float x0f = floorf(x);
      int x0 = (int)x0f;
      s_ix0[o] = x0;
      s_ix1[o] = min(x0 + 1, H - 1);
      s_lx[o] = x - x0f;
      s_vx[o] = v;
    }
  }
  __syncthreads();

  // ---- roi-align, channels-last: wave = pooled cell, lane = 4 channels ----
  const int l = t & 63;
  const int w = t >> 6;
  const int c4 = l * 4;

  for (int cell = w; cell < 98; cell += 4) {
    const int rr = (cell >= 49) ? 1 : 0;
    const int pos = cell - rr * 49;
    const int py = pos / 7, px = pos - (pos / 7) * 7;
    const ushort_t* clb = clb_[rr];
    const int W = W_[rr];
    float a0 = 0.f, a1 = 0.f, a2 = 0.f, a3 = 0.f;
#pragma unroll
    for (int sy = 0; sy < 2; ++sy) {
      const int gy = rr * G_ + 2 * py + sy;
      const int iy0 = s_iy0[gy], iy1 = s_iy1[gy];
      const float ly = s_ly[gy], vy = s_vy[gy];
      const float hy = 1.0f - ly;
#pragma unroll
      for (int sx = 0; sx < 2; ++sx) {
        const int gx = rr * G_ + 2 * px + sx;
        const int ix0 = s_ix0[gx], ix1 = s_ix1[gx];
        const float lx = s_lx[gx], vx = s_vx[gx];
        const float hx = 1.0f - lx;
        const float vv = vy * vx;
        const float w00 = vv * hy * hx, w01 = vv * hy * lx;
        const float w10 = vv * ly * hx, w11 = vv * ly * lx;
        const ushort4_t u00 = *(const ushort4_t*)(clb + ((size_t)(iy0 * W + ix0) * 256 + c4));
        const ushort4_t u01 = *(const ushort4_t*)(clb + ((size_t)(iy0 * W + ix1) * 256 + c4));
        const ushort4_t u10 = *(const ushort4_t*)(clb + ((size_t)(iy1 * W + ix0) * 256 + c4));
        const ushort4_t u11 = *(const ushort4_t*)(clb + ((size_t)(iy1 * W + ix1) * 256 + c4));
        a0 += w00 * bf2f(u00[0]) + w01 * bf2f(u01[0]) + w10 * bf2f(u10[0]) + w11 * bf2f(u11[0]);
        a1 += w00 * bf2f(u00[1]) + w01 * bf2f(u01[1]) + w10 * bf2f(u10[1]) + w11 * bf2f(u11[1]);
        a2 += w00 * bf2f(u00[2]) + w01 * bf2f(u01[2]) + w10 * bf2f(u10[2]) + w11 * bf2f(u11[2]);
        a3 += w00 * bf2f(u00[3]) + w01 * bf2f(u01[3]) + w10 * bf2f(u10[3]) + w11 * bf2f(u11[3]);
      }
    }
    ushort4_t pv;
    pv[0] = f2bf(a0 * 0.25f);
    pv[1] = f2bf(a1 * 0.25f);
    pv[2] = f2bf(a2 * 0.25f);
    pv[3] = f2bf(a3 * 0.25f);
    *(ushort4_t*)&s_pool[(rr * 50 + pos) * POOL_PITCH + c4] = pv;
  }
  // (pool visibility guaranteed by the K-loop's first barrier)

  // ---- MFMA conv ----------------------------------------------------------
  const int ml = l & 31;
  const int quad = l >> 5;
  const int co_base = w * 64;

  const int pA = ml;       // pos tile 0/2
  const int pB = ml + 32;  // pos tile 1/3 (valid < 49)
  const int pyA = pA / 7, pxA = pA % 7;
  const int pyB = pB / 7, pxB = pB % 7;

  floatx16 acc[8];
#pragma unroll
  for (int a = 0; a < 8; ++a)
#pragma unroll
    for (int i = 0; i < 16; ++i) acc[a][i] = 0.f;

  int kk_next = 2;
  for (int j = 0; j < 9; ++j) {
    const int dy = j / 3 - 1, dx = j % 3 - 1;
    int bnA, bnB;
    {
      const int ry = pyA + dy, rx = pxA + dx;
      const bool ok = (ry >= 0) & (ry < 7) & (rx >= 0) & (rx < 7);
      bnA = ok ? ry * 7 + rx : 49;
    }
    {
      const int ry = pyB + dy, rx = pxB + dx;
      const bool ok = (pB < 49) & (ry >= 0) & (ry < 7) & (rx >= 0) & (rx < 7);
      bnB = ok ? ry * 7 + rx : 49;
    }
    const int row0 = bnA, row1 = bnB, row2 = 50 + bnA, row3 = 50 + bnB;

    for (int kc = 0; kc < 16; ++kc) {
      __syncthreads();
      *(short8*)&s_chunk[t * CHUNK_PITCH] = cur0;
      *(short8*)&s_chunk[t * CHUNK_PITCH + 8] = cur1;
      __syncthreads();
      cur0 = nxt0;
      cur1 = nxt1;
      if (kk_next < 144) {
        const ushort_t* np = wbase + kk_next * 16;
        nxt0 = *(const short8*)(np);
        nxt1 = *(const short8*)(np + 8);
        ++kk_next;
      }
      const short8 a0 =
          *(const short8*)&s_chunk[(co_base + ml) * CHUNK_PITCH + quad * 8];
      const short8 a1 = *(
          const short8*)&s_chunk[(co_base + 32 + ml) * CHUNK_PITCH + quad * 8];
      const int cof = kc * 16 + quad * 8;
      const short8 b0 = *(const short8*)&s_pool[row0 * POOL_PITCH + cof];
      const short8 b1 = *(const short8*)&s_pool[row1 * POOL_PITCH + cof];
      const short8 b2 = *(const short8*)&s_pool[row2 * POOL_PITCH + cof];
      const short8 b3 = *(const short8*)&s_pool[row3 * POOL_PITCH + cof];
      acc[0] = __builtin_amdgcn_mfma_f32_32x32x16_bf16(a0, b0, acc[0], 0, 0, 0);
      acc[1] = __builtin_amdgcn_mfma_f32_32x32x16_bf16(a0, b1, acc[1], 0, 0, 0);
      acc[2] = __builtin_amdgcn_mfma_f32_32x32x16_bf16(a0, b2, acc[2], 0, 0, 0);
      acc[3] = __builtin_amdgcn_mfma_f32_32x32x16_bf16(a0, b3, acc[3], 0, 0, 0);
      acc[4] = __builtin_amdgcn_mfma_f32_32x32x16_bf16(a1, b0, acc[4], 0, 0, 0);
      acc[5] = __builtin_amdgcn_mfma_f32_32x32x16_bf16(a1, b1, acc[5], 0, 0, 0);
      acc[6] = __builtin_amdgcn_mfma_f32_32x32x16_bf16(a1, b2, acc[6], 0, 0, 0);
      acc[7] = __builtin_amdgcn_mfma_f32_32x32x16_bf16(a1, b3, acc[7], 0, 0, 0);
    }
  }
  __syncthreads();  // all pool reads done before h overwrites it

  // ---- epilogue: bias + relu -> h in LDS (fc-k order: [rr][co*49+pos]) ----
  ushort_t* h_lds = s_pool;
#pragma unroll
  for (int cs = 0; cs < 2; ++cs) {
#pragma unroll
    for (int reg = 0; reg < 16; ++reg) {
      const int co = co_base + cs * 32 + (reg & 3) + 8 * (reg >> 2) + 4 * quad;
      const float cb = conv_b[co];
      const int base = co * 49;
      h_lds[base + pA] = f2bf(fmaxf(acc[cs * 4 + 0][reg] + cb, 0.f));
      h_lds[12544 + base + pA] = f2bf(fmaxf(acc[cs * 4 + 2][reg] + cb, 0.f));
      if (pB < 49) {
        h_lds[base + pB] = f2bf(fmaxf(acc[cs * 4 + 1][reg] + cb, 0.f));
        h_lds[12544 + base + pB] = f2bf(fmaxf(acc[cs * 4 + 3][reg] + cb, 0.f));
      }
    }
  }
  __syncthreads();

  // ---- FC(12544 -> 21) per roi: wave-parallel over (roi, class) tasks -----
  for (int task = w; task < 2 * NCLS; task += 4) {
    const int rr = task / NCLS;
    const int c = task - rr * NCLS;
    const ushort_t* fr = fwb + (size_t)c * 12544;
    const ushort_t* hr = h_lds + rr * 12544;
    float s = 0.f;
    for (int it = 0; it < 25; ++it) {
      const int slot = it * 64 + l;
      if (slot < 1568) {
        const short8 wv = *(const short8*)(fr + slot * 8);
        const short8 hv = *(const short8*)(hr + slot * 8);
#pragma unroll
        for (int i = 0; i < 8; ++i)
          s += bf2f((ushort_t)wv[i]) * bf2f((ushort_t)hv[i]);
      }
    }
#pragma unroll
    for (int off = 32; off > 0; off >>= 1) s += __shfl_down(s, off, 64);
    if (l == 0) out[(size_t)(g * 2 + rr) * NCLS + c] = s + fc_b[c];
  }
}

// ---------------------------------------------------------------------------
// Matching: one thread per proposal.
// ---------------------------------------------------------------------------
__global__ void match_kernel(const float* __restrict__ p3,
                             const float* __restrict__ p4,
                             const float* __restrict__ p5,
                             const float* __restrict__ gt,
                             float* __restrict__ out) {
  const int g = blockIdx.x * blockDim.x + threadIdx.x;
  if (g >= NROI_TOT) return;
  const int b = g / PROPS_PER_IMG;
  const int i = g - b * PROPS_PER_IMG;
  const int lvl = i >> 8;
  const int r = i & 255;
  const float* prop =
      (lvl == 0 ? p3 : (lvl == 1 ? p4 : p5)) + (size_t)(b * R_ + r) * 4;
  const float px1 = prop[0], py1 = prop[1], px2 = prop[2], py2 = prop[3];
  const float a1 = (px2 - px1) * (py2 - py1);
  const float* gtb = gt + (size_t)b * M_ * 5;

  float best = -2.f;
  int bi = 0;
  for (int j = 0; j < M_; ++j) {
    const float gx1 = gtb[j * 5 + 0], gy1 = gtb[j * 5 + 1];
    const float gx2 = gtb[j * 5 + 2], gy2 = gtb[j * 5 + 3];
    const float cls = gtb[j * 5 + 4];
    const float tlx = fmaxf(px1, gx1), tly = fmaxf(py1, gy1);
    const float brx = fminf(px2, gx2), bry = fminf(py2, gy2);
    const float iw = fmaxf(brx - tlx, 0.f), ih = fmaxf(bry - tly, 0.f);
    const float inter = iw * ih;
    const float a2 = (gx2 - gx1) * (gy2 - gy1);
    const float iou = inter / ((a1 + a2) - inter);
    const float m = (cls != -1.0f) ? iou : -1.0f;
    if (m > best) { best = m; bi = j; }
  }
  float o0, o1, o2, o3, o4;
  if (best <= 0.4f) {
    o0 = o1 = o2 = o3 = o4 = -1.0f;
  } else if (best < 0.6f) {
    o0 = o1 = o2 = o3 = o4 = -1e8f;
  } else {
    o0 = gtb[bi * 5 + 0]; o1 = gtb[bi * 5 + 1]; o2 = gtb[bi * 5 + 2];
    o3 = gtb[bi * 5 + 3]; o4 = gtb[bi * 5 + 4];
  }
  float* od = out + (size_t)NROI_TOT * NCLS + (size_t)g * 5;
  od[0] = o0; od[1] = o1; od[2] = o2; od[3] = o3; od[4] = o4;
}

extern "C" void kernel_launch(void* const* d_in, const int* in_sizes, int n_in,
                              void* d_out, int out_size, void* d_ws,
                              size_t ws_size, hipStream_t stream) {
  const float* f3 = (const float*)d_in[0];
  const float* f4 = (const float*)d_in[1];
  const float* f5 = (const float*)d_in[2];
  const float* p3 = (const float*)d_in[3];
  const float* p4 = (const float*)d_in[4];
  const float* p5 = (const float*)d_in[5];
  const float* gt = (const float*)d_in[6];
  const float* cw = (const float*)d_in[7];
  const float* cb = (const float*)d_in[8];
  const float* fw = (const float*)d_in[9];
  const float* fb = (const float*)d_in[10];
  float* out = (float*)d_out;

  ushort_t* wsp = (ushort_t*)d_ws;
  ushort_t* wr = wsp;
  ushort_t* fwb = wsp + OFF_FWB;
  ushort_t* cl3 = wsp + OFF_CL3;
  ushort_t* cl4 = wsp + OFF_CL4;
  ushort_t* cl5 = wsp + OFF_CL5;

  prep_w_kernel<<<512, 256, 0, stream>>>(cw, fw, wr, fwb);
  prep_feats_kernel<<<448, 256, 0, stream>>>(f3, f4, f5, cl3, cl4, cl5);
  cls_head_kernel<<<NROI_TOT / 2, 256, 0, stream>>>(cl3, cl4, cl5, p3, p4, p5,
                                                    wr, cb, fwb, fb, out);
  match_kernel<<<(NROI_TOT + 255) / 256, 256, 0, stream>>>(p3, p4, p5, gt, out);
}

// Round 5
// 451.474 us; speedup vs baseline: 6.9481x; 1.2415x over previous
//
#include <hip/hip_runtime.h>

typedef unsigned short ushort_t;
typedef __attribute__((ext_vector_type(4))) unsigned short ushort4_t;
typedef __attribute__((ext_vector_type(8))) short short8;
typedef __attribute__((ext_vector_type(16))) float floatx16;

#define B_ 4
#define C_ 256
#define R_ 256
#define M_ 40
#define NCLS 21
#define ROI_ 7
#define G_ 14
#define NROI_TOT 3072
#define PROPS_PER_IMG 768
#define POOL_PITCH 264   // ushorts per pool row (528 B, 16B-aligned)
#define WCONV_ELEMS (256 * 2304)   // = 144 chunks * 4096
#define WFC_ELEMS (21 * 12544)
// ws layout (ushort offsets)
#define OFF_FWB   WCONV_ELEMS
#define OFF_CL3   (OFF_FWB + WFC_ELEMS)
#define OFF_CL4   (OFF_CL3 + 4 * 64 * 64 * 256)
#define OFF_CL5   (OFF_CL4 + 4 * 32 * 32 * 256)

__device__ __forceinline__ ushort_t f2bf(float f) {
  unsigned u = __builtin_bit_cast(unsigned, f);
  u += 0x7fff + ((u >> 16) & 1);  // RNE
  return (ushort_t)(u >> 16);
}
__device__ __forceinline__ float bf2f(ushort_t h) {
  unsigned u = ((unsigned)h) << 16;
  return __builtin_bit_cast(float, u);
}

// ---------------------------------------------------------------------------
// K0a: conv_w fp32 [co][ci][3][3] -> bf16 chunk-major wr2[kk][co][i]
//      (k = j*256+ci, kk = k/16, i = k%16; each 8 KB chunk contiguous).
//      fc_w -> bf16 flat.
// ---------------------------------------------------------------------------
__global__ void prep_w_kernel(const float* __restrict__ cw,
                              const float* __restrict__ fw,
                              ushort_t* __restrict__ wr,
                              ushort_t* __restrict__ fwb) {
  const int i0 = blockIdx.x * blockDim.x + threadIdx.x;
  const int stride = gridDim.x * blockDim.x;
  for (int idx = i0; idx < WCONV_ELEMS; idx += stride) {
    const int kk = idx >> 12;
    const int rem = idx & 4095;
    const int co = rem >> 4;
    const int i = rem & 15;
    const int k = kk * 16 + i;
    const int j = k >> 8;
    const int ci = k & 255;
    wr[idx] = f2bf(cw[(co * 256 + ci) * 9 + j]);
  }
  for (int idx = i0; idx < WFC_ELEMS; idx += stride) fwb[idx] = f2bf(fw[idx]);
}

// ---------------------------------------------------------------------------
// K0b: feats fp32 [b][c][y][x] -> channels-last bf16 [b][y][x][c].
// ---------------------------------------------------------------------------
__global__ __launch_bounds__(256) void prep_feats_kernel(
    const float* __restrict__ f3, const float* __restrict__ f4,
    const float* __restrict__ f5, ushort_t* __restrict__ cl3,
    ushort_t* __restrict__ cl4, ushort_t* __restrict__ cl5) {
  __shared__ ushort_t tile[64 * 257];
  const int id = blockIdx.x;
  const int t = threadIdx.x;
  const float* in;
  ushort_t* outp;
  int b, y, W;
  if (id < 256) { in = f3; outp = cl3; W = 64; b = id >> 6; y = id & 63; }
  else if (id < 384) { in = f4; outp = cl4; W = 32; b = (id - 256) >> 5; y = (id - 256) & 31; }
  else { in = f5; outp = cl5; W = 16; b = (id - 384) >> 4; y = (id - 384) & 15; }

  for (int idx = t; idx < 256 * W; idx += 256) {
    const int c = idx / W;
    const int x = idx - c * W;
    tile[x * 257 + c] = f2bf(in[((size_t)(b * 256 + c) * W + y) * W + x]);
  }
  __syncthreads();
  ushort_t* orow = outp + ((size_t)(b * W + y) * W) * 256;
  for (int idx = t; idx < W * 64; idx += 256) {
    const int x = idx >> 6;
    const int c4 = (idx & 63) * 4;
    ushort4_t v;
    v[0] = tile[x * 257 + c4 + 0];
    v[1] = tile[x * 257 + c4 + 1];
    v[2] = tile[x * 257 + c4 + 2];
    v[3] = tile[x * 257 + c4 + 3];
    *(ushort4_t*)(orow + (size_t)x * 256 + c4) = v;
  }
}

// ---------------------------------------------------------------------------
// K1: fused roi-align (channels-last) -> barrier-free MFMA conv3x3 K-loop
//     (A direct-from-global coalesced, B from LDS pool) -> relu -> FC.
//     One block (4 waves) per 2 rois.
// ---------------------------------------------------------------------------
__global__ __launch_bounds__(256, 2) void cls_head_kernel(
    const ushort_t* __restrict__ cl3, const ushort_t* __restrict__ cl4,
    const ushort_t* __restrict__ cl5, const float* __restrict__ p3,
    const float* __restrict__ p4, const float* __restrict__ p5,
    const ushort_t* __restrict__ wr, const float* __restrict__ conv_b,
    const ushort_t* __restrict__ fwb, const float* __restrict__ fc_b,
    float* __restrict__ out) {
  __shared__ __align__(16) ushort_t s_pool[2 * 50 * POOL_PITCH];  // 52.8 KB
  __shared__ int s_iy0[28], s_iy1[28], s_ix0[28], s_ix1[28];
  __shared__ float s_ly[28], s_lx[28], s_vy[28], s_vx[28];

  const int g = blockIdx.x;
  const int t = threadIdx.x;

  // per-roi metadata
  const ushort_t* clb_[2];
  int W_[2];
  const float* prop_[2];
#pragma unroll
  for (int rr = 0; rr < 2; ++rr) {
    const int rid = g * 2 + rr;
    const int b = rid / PROPS_PER_IMG;
    const int rem = rid - b * PROPS_PER_IMG;
    const int lvl = rem >> 8;
    const int r = rem & 255;
    const ushort_t* base;
    const float* pp;
    int Wl;
    if (lvl == 0) { base = cl3; pp = p3; Wl = 64; }
    else if (lvl == 1) { base = cl4; pp = p4; Wl = 32; }
    else { base = cl5; pp = p5; Wl = 16; }
    clb_[rr] = base + (size_t)b * Wl * Wl * 256;
    W_[rr] = Wl;
    prop_[rr] = pp + (size_t)(b * R_ + r) * 4;
  }

  // zero rows 49/99 (im2col zero-row per roi)
  s_pool[49 * POOL_PITCH + t] = 0;
  s_pool[99 * POOL_PITCH + t] = 0;

  // ---- axis tables for both rois ------------------------------------------
  if (t < 56) {
    const int rr = t / 28;
    const int tt = t - rr * 28;
    const float* prop = prop_[rr];
    const int H = W_[rr];
    const float scale = 1.0f / (float)(H == 64 ? 8 : (H == 32 ? 16 : 32));
    const float bx1 = prop[0], by1 = prop[1], bx2 = prop[2], by2 = prop[3];
    const float ax = bx1 * scale - 0.5f;
    const float ay = by1 * scale - 0.5f;
    const float rw = bx2 * scale - 0.5f - ax;
    const float rh = by2 * scale - 0.5f - ay;
    const int i = (tt < G_) ? tt : (tt - G_);
    const float frac = ((float)i + 0.5f) / (float)G_;
    const int o = rr * G_ + i;
    if (tt < G_) {
      float yy = ay + frac * rh;
      float v = (yy >= -1.0f && yy <= (float)H) ? 1.0f : 0.0f;
      float y = fminf(fmaxf(yy, 0.0f), (float)(H - 1));
      float y0f = floorf(y);
      int y0 = (int)y0f;
      s_iy0[o] = y0;
      s_iy1[o] = min(y0 + 1, H - 1);
      s_ly[o] = y - y0f;
      s_vy[o] = v;
    } else {
      float xx = ax + frac * rw;
      float v = (xx >= -1.0f && xx <= (float)H) ? 1.0f : 0.0f;
      float x = fminf(fmaxf(xx, 0.0f), (float)(H - 1));
      float x0f = floorf(x);
      int x0 = (int)x0f;
      s_ix0[o] = x0;
      s_ix1[o] = min(x0 + 1, H - 1);
      s_lx[o] = x - x0f;
      s_vx[o] = v;
    }
  }
  __syncthreads();

  // ---- roi-align, channels-last: wave = pooled cell, lane = 4 channels ----
  const int l = t & 63;
  const int w = t >> 6;
  const int c4 = l * 4;

  for (int cell = w; cell < 98; cell += 4) {
    const int rr = (cell >= 49) ? 1 : 0;
    const int pos = cell - rr * 49;
    const int py = pos / 7, px = pos - (pos / 7) * 7;
    const ushort_t* clb = clb_[rr];
    const int W = W_[rr];
    float a0 = 0.f, a1 = 0.f, a2 = 0.f, a3 = 0.f;
#pragma unroll
    for (int sy = 0; sy < 2; ++sy) {
      const int gy = rr * G_ + 2 * py + sy;
      const int iy0 = s_iy0[gy], iy1 = s_iy1[gy];
      const float ly = s_ly[gy], vy = s_vy[gy];
      const float hy = 1.0f - ly;
#pragma unroll
      for (int sx = 0; sx < 2; ++sx) {
        const int gx = rr * G_ + 2 * px + sx;
        const int ix0 = s_ix0[gx], ix1 = s_ix1[gx];
        const float lx = s_lx[gx], vx = s_vx[gx];
        const float hx = 1.0f - lx;
        const float vv = vy * vx;
        const float w00 = vv * hy * hx, w01 = vv * hy * lx;
        const float w10 = vv * ly * hx, w11 = vv * ly * lx;
        const ushort4_t u00 = *(const ushort4_t*)(clb + ((size_t)(iy0 * W + ix0) * 256 + c4));
        const ushort4_t u01 = *(const ushort4_t*)(clb + ((size_t)(iy0 * W + ix1) * 256 + c4));
        const ushort4_t u10 = *(const ushort4_t*)(clb + ((size_t)(iy1 * W + ix0) * 256 + c4));
        const ushort4_t u11 = *(const ushort4_t*)(clb + ((size_t)(iy1 * W + ix1) * 256 + c4));
        a0 += w00 * bf2f(u00[0]) + w01 * bf2f(u01[0]) + w10 * bf2f(u10[0]) + w11 * bf2f(u11[0]);
        a1 += w00 * bf2f(u00[1]) + w01 * bf2f(u01[1]) + w10 * bf2f(u10[1]) + w11 * bf2f(u11[1]);
        a2 += w00 * bf2f(u00[2]) + w01 * bf2f(u01[2]) + w10 * bf2f(u10[2]) + w11 * bf2f(u11[2]);
        a3 += w00 * bf2f(u00[3]) + w01 * bf2f(u01[3]) + w10 * bf2f(u10[3]) + w11 * bf2f(u11[3]);
      }
    }
    ushort4_t pv;
    pv[0] = f2bf(a0 * 0.25f);
    pv[1] = f2bf(a1 * 0.25f);
    pv[2] = f2bf(a2 * 0.25f);
    pv[3] = f2bf(a3 * 0.25f);
    *(ushort4_t*)&s_pool[(rr * 50 + pos) * POOL_PITCH + c4] = pv;
  }
  __syncthreads();  // pool + zero rows visible to all waves

  // ---- MFMA conv: barrier-free K-loop, A direct from global ---------------
  const int ml = l & 31;
  const int quad = l >> 5;
  const int co_base = w * 64;

  const int pA = ml;
  const int pB = ml + 32;
  const int pyA = pA / 7, pxA = pA % 7;
  const int pyB = pB / 7, pxB = pB % 7;

  floatx16 acc[8];
#pragma unroll
  for (int a = 0; a < 8; ++a)
#pragma unroll
    for (int i = 0; i < 16; ++i) acc[a][i] = 0.f;

  // lane's A addresses within a chunk: wr[kk*4096 + co*16 + quad*8]
  const ushort_t* a0p = wr + (co_base + ml) * 16 + quad * 8;
  const ushort_t* a1p = a0p + 32 * 16;

  int kk = 0;
  for (int j = 0; j < 9; ++j) {
    const int dy = j / 3 - 1, dx = j % 3 - 1;
    int bnA, bnB;
    {
      const int ry = pyA + dy, rx = pxA + dx;
      const bool ok = (ry >= 0) & (ry < 7) & (rx >= 0) & (rx < 7);
      bnA = ok ? ry * 7 + rx : 49;
    }
    {
      const int ry = pyB + dy, rx = pxB + dx;
      const bool ok = (pB < 49) & (ry >= 0) & (ry < 7) & (rx >= 0) & (rx < 7);
      bnB = ok ? ry * 7 + rx : 49;
    }
    const int row0 = bnA, row1 = bnB, row2 = 50 + bnA, row3 = 50 + bnB;

#pragma unroll 4
    for (int kc = 0; kc < 16; ++kc, ++kk) {
      const short8 a0 = *(const short8*)(a0p + kk * 4096);
      const short8 a1 = *(const short8*)(a1p + kk * 4096);
      const int cof = kc * 16 + quad * 8;
      const short8 b0 = *(const short8*)&s_pool[row0 * POOL_PITCH + cof];
      const short8 b1 = *(const short8*)&s_pool[row1 * POOL_PITCH + cof];
      const short8 b2 = *(const short8*)&s_pool[row2 * POOL_PITCH + cof];
      const short8 b3 = *(const short8*)&s_pool[row3 * POOL_PITCH + cof];
      acc[0] = __builtin_amdgcn_mfma_f32_32x32x16_bf16(a0, b0, acc[0], 0, 0, 0);
      acc[1] = __builtin_amdgcn_mfma_f32_32x32x16_bf16(a0, b1, acc[1], 0, 0, 0);
      acc[2] = __builtin_amdgcn_mfma_f32_32x32x16_bf16(a0, b2, acc[2], 0, 0, 0);
      acc[3] = __builtin_amdgcn_mfma_f32_32x32x16_bf16(a0, b3, acc[3], 0, 0, 0);
      acc[4] = __builtin_amdgcn_mfma_f32_32x32x16_bf16(a1, b0, acc[4], 0, 0, 0);
      acc[5] = __builtin_amdgcn_mfma_f32_32x32x16_bf16(a1, b1, acc[5], 0, 0, 0);
      acc[6] = __builtin_amdgcn_mfma_f32_32x32x16_bf16(a1, b2, acc[6], 0, 0, 0);
      acc[7] = __builtin_amdgcn_mfma_f32_32x32x16_bf16(a1, b3, acc[7], 0, 0, 0);
    }
  }
  __syncthreads();  // all pool reads done before h overwrites it

  // ---- epilogue: bias + relu -> h in LDS (fc-k order: [rr][co*49+pos]) ----
  ushort_t* h_lds = s_pool;
#pragma unroll
  for (int cs = 0; cs < 2; ++cs) {
#pragma unroll
    for (int reg = 0; reg < 16; ++reg) {
      const int co = co_base + cs * 32 + (reg & 3) + 8 * (reg >> 2) + 4 * quad;
      const float cb = conv_b[co];
      const int base = co * 49;
      h_lds[base + pA] = f2bf(fmaxf(acc[cs * 4 + 0][reg] + cb, 0.f));
      h_lds[12544 + base + pA] = f2bf(fmaxf(acc[cs * 4 + 2][reg] + cb, 0.f));
      if (pB < 49) {
        h_lds[base + pB] = f2bf(fmaxf(acc[cs * 4 + 1][reg] + cb, 0.f));
        h_lds[12544 + base + pB] = f2bf(fmaxf(acc[cs * 4 + 3][reg] + cb, 0.f));
      }
    }
  }
  __syncthreads();

  // ---- FC(12544 -> 21): one task per class, both rois (fc_w read once) ----
  for (int c = w; c < NCLS; c += 4) {
    const ushort_t* fr = fwb + (size_t)c * 12544;
    float s0 = 0.f, s1 = 0.f;
    for (int it = 0; it < 25; ++it) {
      const int slot = it * 64 + l;
      if (slot < 1568) {
        const short8 wv = *(const short8*)(fr + slot * 8);
        const short8 h0 = *(const short8*)(h_lds + slot * 8);
        const short8 h1 = *(const short8*)(h_lds + 12544 + slot * 8);
#pragma unroll
        for (int i = 0; i < 8; ++i) {
          const float wf = bf2f((ushort_t)wv[i]);
          s0 += wf * bf2f((ushort_t)h0[i]);
          s1 += wf * bf2f((ushort_t)h1[i]);
        }
      }
    }
#pragma unroll
    for (int off = 32; off > 0; off >>= 1) {
      s0 += __shfl_down(s0, off, 64);
      s1 += __shfl_down(s1, off, 64);
    }
    if (l == 0) {
      out[(size_t)(g * 2 + 0) * NCLS + c] = s0 + fc_b[c];
      out[(size_t)(g * 2 + 1) * NCLS + c] = s1 + fc_b[c];
    }
  }
}

// ---------------------------------------------------------------------------
// Matching: one thread per proposal.
// ---------------------------------------------------------------------------
__global__ void match_kernel(const float* __restrict__ p3,
                             const float* __restrict__ p4,
                             const float* __restrict__ p5,
                             const float* __restrict__ gt,
                             float* __restrict__ out) {
  const int g = blockIdx.x * blockDim.x + threadIdx.x;
  if (g >= NROI_TOT) return;
  const int b = g / PROPS_PER_IMG;
  const int i = g - b * PROPS_PER_IMG;
  const int lvl = i >> 8;
  const int r = i & 255;
  const float* prop =
      (lvl == 0 ? p3 : (lvl == 1 ? p4 : p5)) + (size_t)(b * R_ + r) * 4;
  const float px1 = prop[0], py1 = prop[1], px2 = prop[2], py2 = prop[3];
  const float a1 = (px2 - px1) * (py2 - py1);
  const float* gtb = gt + (size_t)b * M_ * 5;

  float best = -2.f;
  int bi = 0;
  for (int j = 0; j < M_; ++j) {
    const float gx1 = gtb[j * 5 + 0], gy1 = gtb[j * 5 + 1];
    const float gx2 = gtb[j * 5 + 2], gy2 = gtb[j * 5 + 3];
    const float cls = gtb[j * 5 + 4];
    const float tlx = fmaxf(px1, gx1), tly = fmaxf(py1, gy1);
    const float brx = fminf(px2, gx2), bry = fminf(py2, gy2);
    const float iw = fmaxf(brx - tlx, 0.f), ih = fmaxf(bry - tly, 0.f);
    const float inter = iw * ih;
    const float a2 = (gx2 - gx1) * (gy2 - gy1);
    const float iou = inter / ((a1 + a2) - inter);
    const float m = (cls != -1.0f) ? iou : -1.0f;
    if (m > best) { best = m; bi = j; }
  }
  float o0, o1, o2, o3, o4;
  if (best <= 0.4f) {
    o0 = o1 = o2 = o3 = o4 = -1.0f;
  } else if (best < 0.6f) {
    o0 = o1 = o2 = o3 = o4 = -1e8f;
  } else {
    o0 = gtb[bi * 5 + 0]; o1 = gtb[bi * 5 + 1]; o2 = gtb[bi * 5 + 2];
    o3 = gtb[bi * 5 + 3]; o4 = gtb[bi * 5 + 4];
  }
  float* od = out + (size_t)NROI_TOT * NCLS + (size_t)g * 5;
  od[0] = o0; od[1] = o1; od[2] = o2; od[3] = o3; od[4] = o4;
}

extern "C" void kernel_launch(void* const* d_in, const int* in_sizes, int n_in,
                              void* d_out, int out_size, void* d_ws,
                              size_t ws_size, hipStream_t stream) {
  const float* f3 = (const float*)d_in[0];
  const float* f4 = (const float*)d_in[1];
  const float* f5 = (const float*)d_in[2];
  const float* p3 = (const float*)d_in[3];
  const float* p4 = (const float*)d_in[4];
  const float* p5 = (const float*)d_in[5];
  const float* gt = (const float*)d_in[6];
  const float* cw = (const float*)d_in[7];
  const float* cb = (const float*)d_in[8];
  const float* fw = (const float*)d_in[9];
  const float* fb = (const float*)d_in[10];
  float* out = (float*)d_out;

  ushort_t* wsp = (ushort_t*)d_ws;
  ushort_t* wr = wsp;
  ushort_t* fwb = wsp + OFF_FWB;
  ushort_t* cl3 = wsp + OFF_CL3;
  ushort_t* cl4 = wsp + OFF_CL4;
  ushort_t* cl5 = wsp + OFF_CL5;

  prep_w_kernel<<<512, 256, 0, stream>>>(cw, fw, wr, fwb);
  prep_feats_kernel<<<448, 256, 0, stream>>>(f3, f4, f5, cl3, cl4, cl5);
  cls_head_kernel<<<NROI_TOT / 2, 256, 0, stream>>>(cl3, cl4, cl5, p3, p4, p5,
                                                    wr, cb, fwb, fb, out);
  match_kernel<<<(NROI_TOT + 255) / 256, 256, 0, stream>>>(p3, p4, p5, gt, out);
}

// Round 6
// 408.537 us; speedup vs baseline: 7.6783x; 1.1051x over previous
//
#include <hip/hip_runtime.h>

typedef unsigned short ushort_t;
typedef __attribute__((ext_vector_type(4))) unsigned short ushort4_t;
typedef __attribute__((ext_vector_type(8))) short short8;
typedef __attribute__((ext_vector_type(16))) float floatx16;

#define B_ 4
#define C_ 256
#define R_ 256
#define M_ 40
#define NCLS 21
#define ROI_ 7
#define G_ 14
#define NROI_TOT 3072
#define PROPS_PER_IMG 768
#define POOL_PITCH 264   // ushorts per pool row (528 B, 16B-aligned)
#define WCONV_ELEMS (256 * 2304)   // = 144 chunks * 4096
#define WFC_ELEMS (21 * 12544)
// ws layout (ushort offsets)
#define OFF_FWB   WCONV_ELEMS
#define OFF_CL3   (OFF_FWB + WFC_ELEMS)
#define OFF_CL4   (OFF_CL3 + 4 * 64 * 64 * 256)
#define OFF_CL5   (OFF_CL4 + 4 * 32 * 32 * 256)

__device__ __forceinline__ ushort_t f2bf(float f) {
  unsigned u = __builtin_bit_cast(unsigned, f);
  u += 0x7fff + ((u >> 16) & 1);  // RNE
  return (ushort_t)(u >> 16);
}
__device__ __forceinline__ float bf2f(ushort_t h) {
  unsigned u = ((unsigned)h) << 16;
  return __builtin_bit_cast(float, u);
}

// ---------------------------------------------------------------------------
// K0a: conv_w fp32 [co][ci][3][3] -> bf16 chunk-major wr2[kk][co][i]
//      (k = j*256+ci, kk = k/16, i = k%16). fc_w -> bf16 flat.
// ---------------------------------------------------------------------------
__global__ void prep_w_kernel(const float* __restrict__ cw,
                              const float* __restrict__ fw,
                              ushort_t* __restrict__ wr,
                              ushort_t* __restrict__ fwb) {
  const int i0 = blockIdx.x * blockDim.x + threadIdx.x;
  const int stride = gridDim.x * blockDim.x;
  for (int idx = i0; idx < WCONV_ELEMS; idx += stride) {
    const int kk = idx >> 12;
    const int rem = idx & 4095;
    const int co = rem >> 4;
    const int i = rem & 15;
    const int k = kk * 16 + i;
    const int j = k >> 8;
    const int ci = k & 255;
    wr[idx] = f2bf(cw[(co * 256 + ci) * 9 + j]);
  }
  for (int idx = i0; idx < WFC_ELEMS; idx += stride) fwb[idx] = f2bf(fw[idx]);
}

// ---------------------------------------------------------------------------
// K0b: feats fp32 [b][c][y][x] -> channels-last bf16 [b][y][x][c].
// ---------------------------------------------------------------------------
__global__ __launch_bounds__(256) void prep_feats_kernel(
    const float* __restrict__ f3, const float* __restrict__ f4,
    const float* __restrict__ f5, ushort_t* __restrict__ cl3,
    ushort_t* __restrict__ cl4, ushort_t* __restrict__ cl5) {
  __shared__ ushort_t tile[64 * 257];
  const int id = blockIdx.x;
  const int t = threadIdx.x;
  const float* in;
  ushort_t* outp;
  int b, y, W;
  if (id < 256) { in = f3; outp = cl3; W = 64; b = id >> 6; y = id & 63; }
  else if (id < 384) { in = f4; outp = cl4; W = 32; b = (id - 256) >> 5; y = (id - 256) & 31; }
  else { in = f5; outp = cl5; W = 16; b = (id - 384) >> 4; y = (id - 384) & 15; }

  for (int idx = t; idx < 256 * W; idx += 256) {
    const int c = idx / W;
    const int x = idx - c * W;
    tile[x * 257 + c] = f2bf(in[((size_t)(b * 256 + c) * W + y) * W + x]);
  }
  __syncthreads();
  ushort_t* orow = outp + ((size_t)(b * W + y) * W) * 256;
  for (int idx = t; idx < W * 64; idx += 256) {
    const int x = idx >> 6;
    const int c4 = (idx & 63) * 4;
    ushort4_t v;
    v[0] = tile[x * 257 + c4 + 0];
    v[1] = tile[x * 257 + c4 + 1];
    v[2] = tile[x * 257 + c4 + 2];
    v[3] = tile[x * 257 + c4 + 3];
    *(ushort4_t*)(orow + (size_t)x * 256 + c4) = v;
  }
}

// ---------------------------------------------------------------------------
// K1: fused roi-align -> barrier-free MFMA conv3x3 -> relu -> FC.
//     512 threads (8 waves) per block, 2 rois per block.
//     Wave w: co tile [32w, 32w+32) x 128 pos (2 rois x 64) -> 4 acc tiles
//     = 64 AGPR -> 4 waves/SIMD occupancy.
// ---------------------------------------------------------------------------
__global__ __launch_bounds__(512, 4) void cls_head_kernel(
    const ushort_t* __restrict__ cl3, const ushort_t* __restrict__ cl4,
    const ushort_t* __restrict__ cl5, const float* __restrict__ p3,
    const float* __restrict__ p4, const float* __restrict__ p5,
    const ushort_t* __restrict__ wr, const float* __restrict__ conv_b,
    const ushort_t* __restrict__ fwb, const float* __restrict__ fc_b,
    float* __restrict__ out) {
  __shared__ __align__(16) ushort_t s_pool[2 * 50 * POOL_PITCH];  // 52.8 KB
  __shared__ int s_iy0[28], s_iy1[28], s_ix0[28], s_ix1[28];
  __shared__ float s_ly[28], s_lx[28], s_vy[28], s_vx[28];

  const int g = blockIdx.x;
  const int t = threadIdx.x;

  // per-roi metadata
  const ushort_t* clb_[2];
  int W_[2];
  const float* prop_[2];
#pragma unroll
  for (int rr = 0; rr < 2; ++rr) {
    const int rid = g * 2 + rr;
    const int b = rid / PROPS_PER_IMG;
    const int rem = rid - b * PROPS_PER_IMG;
    const int lvl = rem >> 8;
    const int r = rem & 255;
    const ushort_t* base;
    const float* pp;
    int Wl;
    if (lvl == 0) { base = cl3; pp = p3; Wl = 64; }
    else if (lvl == 1) { base = cl4; pp = p4; Wl = 32; }
    else { base = cl5; pp = p5; Wl = 16; }
    clb_[rr] = base + (size_t)b * Wl * Wl * 256;
    W_[rr] = Wl;
    prop_[rr] = pp + (size_t)(b * R_ + r) * 4;
  }

  // zero rows 49/99 (im2col zero-row per roi)
  if (t < POOL_PITCH) {
    s_pool[49 * POOL_PITCH + t] = 0;
    s_pool[99 * POOL_PITCH + t] = 0;
  }

  // ---- axis tables for both rois ------------------------------------------
  if (t < 56) {
    const int rr = t / 28;
    const int tt = t - rr * 28;
    const float* prop = prop_[rr];
    const int H = W_[rr];
    const float scale = 1.0f / (float)(H == 64 ? 8 : (H == 32 ? 16 : 32));
    const float bx1 = prop[0], by1 = prop[1], bx2 = prop[2], by2 = prop[3];
    const float ax = bx1 * scale - 0.5f;
    const float ay = by1 * scale - 0.5f;
    const float rw = bx2 * scale - 0.5f - ax;
    const float rh = by2 * scale - 0.5f - ay;
    const int i = (tt < G_) ? tt : (tt - G_);
    const float frac = ((float)i + 0.5f) / (float)G_;
    const int o = rr * G_ + i;
    if (tt < G_) {
      float yy = ay + frac * rh;
      float v = (yy >= -1.0f && yy <= (float)H) ? 1.0f : 0.0f;
      float y = fminf(fmaxf(yy, 0.0f), (float)(H - 1));
      float y0f = floorf(y);
      int y0 = (int)y0f;
      s_iy0[o] = y0;
      s_iy1[o] = min(y0 + 1, H - 1);
      s_ly[o] = y - y0f;
      s_vy[o] = v;
    } else {
      float xx = ax + frac * rw;
      float v = (xx >= -1.0f && xx <= (float)H) ? 1.0f : 0.0f;
      float x = fminf(fmaxf(xx, 0.0f), (float)(H - 1));
      float x0f = floorf(x);
      int x0 = (int)x0f;
      s_ix0[o] = x0;
      s_ix1[o] = min(x0 + 1, H - 1);
      s_lx[o] = x - x0f;
      s_vx[o] = v;
    }
  }
  __syncthreads();

  // ---- roi-align, channels-last: wave = pooled cell, lane = 4 channels ----
  const int l = t & 63;
  const int w = t >> 6;  // 0..7
  const int c4 = l * 4;

  for (int cell = w; cell < 98; cell += 8) {
    const int rr = (cell >= 49) ? 1 : 0;
    const int pos = cell - rr * 49;
    const int py = pos / 7, px = pos - (pos / 7) * 7;
    const ushort_t* clb = clb_[rr];
    const int W = W_[rr];
    float a0 = 0.f, a1 = 0.f, a2 = 0.f, a3 = 0.f;
#pragma unroll
    for (int sy = 0; sy < 2; ++sy) {
      const int gy = rr * G_ + 2 * py + sy;
      const int iy0 = s_iy0[gy], iy1 = s_iy1[gy];
      const float ly = s_ly[gy], vy = s_vy[gy];
      const float hy = 1.0f - ly;
#pragma unroll
      for (int sx = 0; sx < 2; ++sx) {
        const int gx = rr * G_ + 2 * px + sx;
        const int ix0 = s_ix0[gx], ix1 = s_ix1[gx];
        const float lx = s_lx[gx], vx = s_vx[gx];
        const float hx = 1.0f - lx;
        const float vv = vy * vx;
        const float w00 = vv * hy * hx, w01 = vv * hy * lx;
        const float w10 = vv * ly * hx, w11 = vv * ly * lx;
        const ushort4_t u00 = *(const ushort4_t*)(clb + ((size_t)(iy0 * W + ix0) * 256 + c4));
        const ushort4_t u01 = *(const ushort4_t*)(clb + ((size_t)(iy0 * W + ix1) * 256 + c4));
        const ushort4_t u10 = *(const ushort4_t*)(clb + ((size_t)(iy1 * W + ix0) * 256 + c4));
        const ushort4_t u11 = *(const ushort4_t*)(clb + ((size_t)(iy1 * W + ix1) * 256 + c4));
        a0 += w00 * bf2f(u00[0]) + w01 * bf2f(u01[0]) + w10 * bf2f(u10[0]) + w11 * bf2f(u11[0]);
        a1 += w00 * bf2f(u00[1]) + w01 * bf2f(u01[1]) + w10 * bf2f(u10[1]) + w11 * bf2f(u11[1]);
        a2 += w00 * bf2f(u00[2]) + w01 * bf2f(u01[2]) + w10 * bf2f(u10[2]) + w11 * bf2f(u11[2]);
        a3 += w00 * bf2f(u00[3]) + w01 * bf2f(u01[3]) + w10 * bf2f(u10[3]) + w11 * bf2f(u11[3]);
      }
    }
    ushort4_t pv;
    pv[0] = f2bf(a0 * 0.25f);
    pv[1] = f2bf(a1 * 0.25f);
    pv[2] = f2bf(a2 * 0.25f);
    pv[3] = f2bf(a3 * 0.25f);
    *(ushort4_t*)&s_pool[(rr * 50 + pos) * POOL_PITCH + c4] = pv;
  }
  __syncthreads();  // pool + zero rows visible to all waves

  // ---- MFMA conv: barrier-free K-loop, A direct from global ---------------
  const int ml = l & 31;
  const int quad = l >> 5;
  const int co_base = w * 32;

  const int pA = ml;
  const int pB = ml + 32;
  const int pyA = pA / 7, pxA = pA % 7;
  const int pyB = pB / 7, pxB = pB % 7;

  floatx16 acc[4];
#pragma unroll
  for (int a = 0; a < 4; ++a)
#pragma unroll
    for (int i = 0; i < 16; ++i) acc[a][i] = 0.f;

  // lane's A address within a chunk: wr[kk*4096 + co*16 + quad*8]
  const ushort_t* a0p = wr + (co_base + ml) * 16 + quad * 8;

  int kk = 0;
  for (int j = 0; j < 9; ++j) {
    const int dy = j / 3 - 1, dx = j % 3 - 1;
    int bnA, bnB;
    {
      const int ry = pyA + dy, rx = pxA + dx;
      const bool ok = (ry >= 0) & (ry < 7) & (rx >= 0) & (rx < 7);
      bnA = ok ? ry * 7 + rx : 49;
    }
    {
      const int ry = pyB + dy, rx = pxB + dx;
      const bool ok = (pB < 49) & (ry >= 0) & (ry < 7) & (rx >= 0) & (rx < 7);
      bnB = ok ? ry * 7 + rx : 49;
    }
    const int row0 = bnA, row1 = bnB, row2 = 50 + bnA, row3 = 50 + bnB;

#pragma unroll 4
    for (int kc = 0; kc < 16; ++kc, ++kk) {
      const short8 a0 = *(const short8*)(a0p + kk * 4096);
      const int cof = kc * 16 + quad * 8;
      const short8 b0 = *(const short8*)&s_pool[row0 * POOL_PITCH + cof];
      const short8 b1 = *(const short8*)&s_pool[row1 * POOL_PITCH + cof];
      const short8 b2 = *(const short8*)&s_pool[row2 * POOL_PITCH + cof];
      const short8 b3 = *(const short8*)&s_pool[row3 * POOL_PITCH + cof];
      acc[0] = __builtin_amdgcn_mfma_f32_32x32x16_bf16(a0, b0, acc[0], 0, 0, 0);
      acc[1] = __builtin_amdgcn_mfma_f32_32x32x16_bf16(a0, b1, acc[1], 0, 0, 0);
      acc[2] = __builtin_amdgcn_mfma_f32_32x32x16_bf16(a0, b2, acc[2], 0, 0, 0);
      acc[3] = __builtin_amdgcn_mfma_f32_32x32x16_bf16(a0, b3, acc[3], 0, 0, 0);
    }
  }
  __syncthreads();  // all pool reads done before h overwrites it

  // ---- epilogue: bias + relu -> h in LDS (fc-k order: [rr][co*49+pos]) ----
  ushort_t* h_lds = s_pool;
#pragma unroll
  for (int reg = 0; reg < 16; ++reg) {
    const int co = co_base + (reg & 3) + 8 * (reg >> 2) + 4 * quad;
    const float cb = conv_b[co];
    const int base = co * 49;
    h_lds[base + pA] = f2bf(fmaxf(acc[0][reg] + cb, 0.f));
    h_lds[12544 + base + pA] = f2bf(fmaxf(acc[2][reg] + cb, 0.f));
    if (pB < 49) {
      h_lds[base + pB] = f2bf(fmaxf(acc[1][reg] + cb, 0.f));
      h_lds[12544 + base + pB] = f2bf(fmaxf(acc[3][reg] + cb, 0.f));
    }
  }
  __syncthreads();

  // ---- FC(12544 -> 21): one task per class, both rois (fc_w read once) ----
  for (int c = w; c < NCLS; c += 8) {
    const ushort_t* fr = fwb + (size_t)c * 12544;
    float s0 = 0.f, s1 = 0.f;
    for (int it = 0; it < 25; ++it) {
      const int slot = it * 64 + l;
      if (slot < 1568) {
        const short8 wv = *(const short8*)(fr + slot * 8);
        const short8 h0 = *(const short8*)(h_lds + slot * 8);
        const short8 h1 = *(const short8*)(h_lds + 12544 + slot * 8);
#pragma unroll
        for (int i = 0; i < 8; ++i) {
          const float wf = bf2f((ushort_t)wv[i]);
          s0 += wf * bf2f((ushort_t)h0[i]);
          s1 += wf * bf2f((ushort_t)h1[i]);
        }
      }
    }
#pragma unroll
    for (int off = 32; off > 0; off >>= 1) {
      s0 += __shfl_down(s0, off, 64);
      s1 += __shfl_down(s1, off, 64);
    }
    if (l == 0) {
      out[(size_t)(g * 2 + 0) * NCLS + c] = s0 + fc_b[c];
      out[(size_t)(g * 2 + 1) * NCLS + c] = s1 + fc_b[c];
    }
  }
}

// ---------------------------------------------------------------------------
// Matching: one thread per proposal.
// ---------------------------------------------------------------------------
__global__ void match_kernel(const float* __restrict__ p3,
                             const float* __restrict__ p4,
                             const float* __restrict__ p5,
                             const float* __restrict__ gt,
                             float* __restrict__ out) {
  const int g = blockIdx.x * blockDim.x + threadIdx.x;
  if (g >= NROI_TOT) return;
  const int b = g / PROPS_PER_IMG;
  const int i = g - b * PROPS_PER_IMG;
  const int lvl = i >> 8;
  const int r = i & 255;
  const float* prop =
      (lvl == 0 ? p3 : (lvl == 1 ? p4 : p5)) + (size_t)(b * R_ + r) * 4;
  const float px1 = prop[0], py1 = prop[1], px2 = prop[2], py2 = prop[3];
  const float a1 = (px2 - px1) * (py2 - py1);
  const float* gtb = gt + (size_t)b * M_ * 5;

  float best = -2.f;
  int bi = 0;
  for (int j = 0; j < M_; ++j) {
    const float gx1 = gtb[j * 5 + 0], gy1 = gtb[j * 5 + 1];
    const float gx2 = gtb[j * 5 + 2], gy2 = gtb[j * 5 + 3];
    const float cls = gtb[j * 5 + 4];
    const float tlx = fmaxf(px1, gx1), tly = fmaxf(py1, gy1);
    const float brx = fminf(px2, gx2), bry = fminf(py2, gy2);
    const float iw = fmaxf(brx - tlx, 0.f), ih = fmaxf(bry - tly, 0.f);
    const float inter = iw * ih;
    const float a2 = (gx2 - gx1) * (gy2 - gy1);
    const float iou = inter / ((a1 + a2) - inter);
    const float m = (cls != -1.0f) ? iou : -1.0f;
    if (m > best) { best = m; bi = j; }
  }
  float o0, o1, o2, o3, o4;
  if (best <= 0.4f) {
    o0 = o1 = o2 = o3 = o4 = -1.0f;
  } else if (best < 0.6f) {
    o0 = o1 = o2 = o3 = o4 = -1e8f;
  } else {
    o0 = gtb[bi * 5 + 0]; o1 = gtb[bi * 5 + 1]; o2 = gtb[bi * 5 + 2];
    o3 = gtb[bi * 5 + 3]; o4 = gtb[bi * 5 + 4];
  }
  float* od = out + (size_t)NROI_TOT * NCLS + (size_t)g * 5;
  od[0] = o0; od[1] = o1; od[2] = o2; od[3] = o3; od[4] = o4;
}

extern "C" void kernel_launch(void* const* d_in, const int* in_sizes, int n_in,
                              void* d_out, int out_size, void* d_ws,
                              size_t ws_size, hipStream_t stream) {
  const float* f3 = (const float*)d_in[0];
  const float* f4 = (const float*)d_in[1];
  const float* f5 = (const float*)d_in[2];
  const float* p3 = (const float*)d_in[3];
  const float* p4 = (const float*)d_in[4];
  const float* p5 = (const float*)d_in[5];
  const float* gt = (const float*)d_in[6];
  const float* cw = (const float*)d_in[7];
  const float* cb = (const float*)d_in[8];
  const float* fw = (const float*)d_in[9];
  const float* fb = (const float*)d_in[10];
  float* out = (float*)d_out;

  ushort_t* wsp = (ushort_t*)d_ws;
  ushort_t* wr = wsp;
  ushort_t* fwb = wsp + OFF_FWB;
  ushort_t* cl3 = wsp + OFF_CL3;
  ushort_t* cl4 = wsp + OFF_CL4;
  ushort_t* cl5 = wsp + OFF_CL5;

  prep_w_kernel<<<512, 256, 0, stream>>>(cw, fw, wr, fwb);
  prep_feats_kernel<<<448, 256, 0, stream>>>(f3, f4, f5, cl3, cl4, cl5);
  cls_head_kernel<<<NROI_TOT / 2, 512, 0, stream>>>(cl3, cl4, cl5, p3, p4, p5,
                                                    wr, cb, fwb, fb, out);
  match_kernel<<<(NROI_TOT + 255) / 256, 256, 0, stream>>>(p3, p4, p5, gt, out);
}

// Round 7
// 393.557 us; speedup vs baseline: 7.9706x; 1.0381x over previous
//
#include <hip/hip_runtime.h>

typedef unsigned short ushort_t;
typedef __attribute__((ext_vector_type(4))) unsigned short ushort4_t;
typedef __attribute__((ext_vector_type(8))) short short8;
typedef __attribute__((ext_vector_type(4))) float floatx4;
typedef __attribute__((ext_vector_type(16))) float floatx16;

#define B_ 4
#define C_ 256
#define R_ 256
#define M_ 40
#define NCLS 21
#define ROI_ 7
#define G_ 14
#define NROI_TOT 3072
#define PROPS_PER_IMG 768
#define POOL_PITCH 264   // ushorts per pool row (528 B, 16B-aligned)
#define WCONV_ELEMS (256 * 2304)   // = 144 chunks * 4096
#define WFC_ELEMS (21 * 12544)
// ws layout (ushort offsets)
#define OFF_FWB   WCONV_ELEMS
#define OFF_CL3   (OFF_FWB + WFC_ELEMS)
#define OFF_CL4   (OFF_CL3 + 4 * 64 * 64 * 256)
#define OFF_CL5   (OFF_CL4 + 4 * 32 * 32 * 256)

__device__ __forceinline__ ushort_t f2bf(float f) {
  unsigned u = __builtin_bit_cast(unsigned, f);
  u += 0x7fff + ((u >> 16) & 1);  // RNE
  return (ushort_t)(u >> 16);
}
__device__ __forceinline__ float bf2f(ushort_t h) {
  unsigned u = ((unsigned)h) << 16;
  return __builtin_bit_cast(float, u);
}

// ---------------------------------------------------------------------------
// K0 (merged): blocks [0,512): conv_w -> bf16 chunk-major wr2[kk][co][i],
//   fc_w -> bf16 flat; blocks [512,960): feats fp32 NCHW -> bf16 NHWC;
//   blocks [960,972): IoU matching.
// ---------------------------------------------------------------------------
__global__ __launch_bounds__(256) void prep_kernel(
    const float* __restrict__ cw, const float* __restrict__ fw,
    const float* __restrict__ f3, const float* __restrict__ f4,
    const float* __restrict__ f5, const float* __restrict__ p3,
    const float* __restrict__ p4, const float* __restrict__ p5,
    const float* __restrict__ gt, ushort_t* __restrict__ wr,
    ushort_t* __restrict__ fwb, ushort_t* __restrict__ cl3,
    ushort_t* __restrict__ cl4, ushort_t* __restrict__ cl5,
    float* __restrict__ out) {
  __shared__ ushort_t tile[64 * 257];
  const int id = blockIdx.x;
  const int t = threadIdx.x;

  if (id < 512) {
    // ---- weights ----
    const int i0 = id * 256 + t;
    const int stride = 512 * 256;
    for (int idx = i0; idx < WCONV_ELEMS; idx += stride) {
      const int kk = idx >> 12;
      const int rem = idx & 4095;
      const int co = rem >> 4;
      const int i = rem & 15;
      const int k = kk * 16 + i;
      const int j = k >> 8;
      const int ci = k & 255;
      wr[idx] = f2bf(cw[(co * 256 + ci) * 9 + j]);
    }
    for (int idx = i0; idx < WFC_ELEMS; idx += stride) fwb[idx] = f2bf(fw[idx]);
  } else if (id < 960) {
    // ---- features NCHW -> NHWC bf16 ----
    const int fid = id - 512;
    const float* in;
    ushort_t* outp;
    int b, y, W;
    if (fid < 256) { in = f3; outp = cl3; W = 64; b = fid >> 6; y = fid & 63; }
    else if (fid < 384) { in = f4; outp = cl4; W = 32; b = (fid - 256) >> 5; y = (fid - 256) & 31; }
    else { in = f5; outp = cl5; W = 16; b = (fid - 384) >> 4; y = (fid - 384) & 15; }

    for (int idx = t; idx < 256 * W; idx += 256) {
      const int c = idx / W;
      const int x = idx - c * W;
      tile[x * 257 + c] = f2bf(in[((size_t)(b * 256 + c) * W + y) * W + x]);
    }
    __syncthreads();
    ushort_t* orow = outp + ((size_t)(b * W + y) * W) * 256;
    for (int idx = t; idx < W * 64; idx += 256) {
      const int x = idx >> 6;
      const int c4 = (idx & 63) * 4;
      ushort4_t v;
      v[0] = tile[x * 257 + c4 + 0];
      v[1] = tile[x * 257 + c4 + 1];
      v[2] = tile[x * 257 + c4 + 2];
      v[3] = tile[x * 257 + c4 + 3];
      *(ushort4_t*)(orow + (size_t)x * 256 + c4) = v;
    }
  } else {
    // ---- matching ----
    const int gidx = (id - 960) * 256 + t;
    if (gidx >= NROI_TOT) return;
    const int b = gidx / PROPS_PER_IMG;
    const int i = gidx - b * PROPS_PER_IMG;
    const int lvl = i >> 8;
    const int r = i & 255;
    const float* prop =
        (lvl == 0 ? p3 : (lvl == 1 ? p4 : p5)) + (size_t)(b * R_ + r) * 4;
    const float px1 = prop[0], py1 = prop[1], px2 = prop[2], py2 = prop[3];
    const float a1 = (px2 - px1) * (py2 - py1);
    const float* gtb = gt + (size_t)b * M_ * 5;

    float best = -2.f;
    int bi = 0;
    for (int j = 0; j < M_; ++j) {
      const float gx1 = gtb[j * 5 + 0], gy1 = gtb[j * 5 + 1];
      const float gx2 = gtb[j * 5 + 2], gy2 = gtb[j * 5 + 3];
      const float cls = gtb[j * 5 + 4];
      const float tlx = fmaxf(px1, gx1), tly = fmaxf(py1, gy1);
      const float brx = fminf(px2, gx2), bry = fminf(py2, gy2);
      const float iw = fmaxf(brx - tlx, 0.f), ih = fmaxf(bry - tly, 0.f);
      const float inter = iw * ih;
      const float a2 = (gx2 - gx1) * (gy2 - gy1);
      const float iou = inter / ((a1 + a2) - inter);
      const float m = (cls != -1.0f) ? iou : -1.0f;
      if (m > best) { best = m; bi = j; }
    }
    float o0, o1, o2, o3, o4;
    if (best <= 0.4f) {
      o0 = o1 = o2 = o3 = o4 = -1.0f;
    } else if (best < 0.6f) {
      o0 = o1 = o2 = o3 = o4 = -1e8f;
    } else {
      o0 = gtb[bi * 5 + 0]; o1 = gtb[bi * 5 + 1]; o2 = gtb[bi * 5 + 2];
      o3 = gtb[bi * 5 + 3]; o4 = gtb[bi * 5 + 4];
    }
    float* od = out + (size_t)NROI_TOT * NCLS + (size_t)gidx * 5;
    od[0] = o0; od[1] = o1; od[2] = o2; od[3] = o3; od[4] = o4;
  }
}

// ---------------------------------------------------------------------------
// K1: fused roi-align -> barrier-free MFMA conv3x3 -> relu -> MFMA FC.
//     512 threads (8 waves) per block, 2 rois per block.
// ---------------------------------------------------------------------------
__global__ __launch_bounds__(512, 4) void cls_head_kernel(
    const ushort_t* __restrict__ cl3, const ushort_t* __restrict__ cl4,
    const ushort_t* __restrict__ cl5, const float* __restrict__ p3,
    const float* __restrict__ p4, const float* __restrict__ p5,
    const ushort_t* __restrict__ wr, const float* __restrict__ conv_b,
    const ushort_t* __restrict__ fwb, const float* __restrict__ fc_b,
    float* __restrict__ out) {
  __shared__ __align__(16) ushort_t s_pool[2 * 50 * POOL_PITCH];  // 52.8 KB
  __shared__ int s_iy0[28], s_iy1[28], s_ix0[28], s_ix1[28];
  __shared__ float s_ly[28], s_lx[28], s_vy[28], s_vx[28];
  __shared__ float s_fcred[512];  // [class(32)][roi(2)][wave(8)]

  const int g = blockIdx.x;
  const int t = threadIdx.x;

  // per-roi metadata
  const ushort_t* clb_[2];
  int W_[2];
  const float* prop_[2];
#pragma unroll
  for (int rr = 0; rr < 2; ++rr) {
    const int rid = g * 2 + rr;
    const int b = rid / PROPS_PER_IMG;
    const int rem = rid - b * PROPS_PER_IMG;
    const int lvl = rem >> 8;
    const int r = rem & 255;
    const ushort_t* base;
    const float* pp;
    int Wl;
    if (lvl == 0) { base = cl3; pp = p3; Wl = 64; }
    else if (lvl == 1) { base = cl4; pp = p4; Wl = 32; }
    else { base = cl5; pp = p5; Wl = 16; }
    clb_[rr] = base + (size_t)b * Wl * Wl * 256;
    W_[rr] = Wl;
    prop_[rr] = pp + (size_t)(b * R_ + r) * 4;
  }

  // zero rows 49/99 (im2col zero-row per roi)
  if (t < POOL_PITCH) {
    s_pool[49 * POOL_PITCH + t] = 0;
    s_pool[99 * POOL_PITCH + t] = 0;
  }

  // ---- axis tables for both rois ------------------------------------------
  if (t < 56) {
    const int rr = t / 28;
    const int tt = t - rr * 28;
    const float* prop = prop_[rr];
    const int H = W_[rr];
    const float scale = 1.0f / (float)(H == 64 ? 8 : (H == 32 ? 16 : 32));
    const float bx1 = prop[0], by1 = prop[1], bx2 = prop[2], by2 = prop[3];
    const float ax = bx1 * scale - 0.5f;
    const float ay = by1 * scale - 0.5f;
    const float rw = bx2 * scale - 0.5f - ax;
    const float rh = by2 * scale - 0.5f - ay;
    const int i = (tt < G_) ? tt : (tt - G_);
    const float frac = ((float)i + 0.5f) / (float)G_;
    const int o = rr * G_ + i;
    if (tt < G_) {
      float yy = ay + frac * rh;
      float v = (yy >= -1.0f && yy <= (float)H) ? 1.0f : 0.0f;
      float y = fminf(fmaxf(yy, 0.0f), (float)(H - 1));
      float y0f = floorf(y);
      int y0 = (int)y0f;
      s_iy0[o] = y0;
      s_iy1[o] = min(y0 + 1, H - 1);
      s_ly[o] = y - y0f;
      s_vy[o] = v;
    } else {
      float xx = ax + frac * rw;
      float v = (xx >= -1.0f && xx <= (float)H) ? 1.0f : 0.0f;
      float x = fminf(fmaxf(xx, 0.0f), (float)(H - 1));
      float x0f = floorf(x);
      int x0 = (int)x0f;
      s_ix0[o] = x0;
      s_ix1[o] = min(x0 + 1, H - 1);
      s_lx[o] = x - x0f;
      s_vx[o] = v;
    }
  }
  __syncthreads();

  const int l = t & 63;
  const int w = t >> 6;  // 0..7

  // ---- roi-align: half-wave per cell, lane covers 8 channels --------------
  {
    const int hw = l >> 5;        // which cell of the pair
    const int c8 = (l & 31) * 8;  // channel offset
    for (int cb = w * 2; cb < 98; cb += 16) {
      const int cell = cb + hw;
      if (cell >= 98) continue;
      const int rr = (cell >= 49) ? 1 : 0;
      const int pos = cell - rr * 49;
      const int py = pos / 7, px = pos - (pos / 7) * 7;
      const ushort_t* clb = clb_[rr];
      const int W = W_[rr];
      float a[8];
#pragma unroll
      for (int i = 0; i < 8; ++i) a[i] = 0.f;
#pragma unroll
      for (int sy = 0; sy < 2; ++sy) {
        const int gy = rr * G_ + 2 * py + sy;
        const int iy0 = s_iy0[gy], iy1 = s_iy1[gy];
        const float ly = s_ly[gy], vy = s_vy[gy];
        const float hy = 1.0f - ly;
#pragma unroll
        for (int sx = 0; sx < 2; ++sx) {
          const int gx = rr * G_ + 2 * px + sx;
          const int ix0 = s_ix0[gx], ix1 = s_ix1[gx];
          const float lx = s_lx[gx], vx = s_vx[gx];
          const float hx = 1.0f - lx;
          const float vv = vy * vx;
          const float w00 = vv * hy * hx, w01 = vv * hy * lx;
          const float w10 = vv * ly * hx, w11 = vv * ly * lx;
          const short8 u00 = *(const short8*)(clb + ((size_t)(iy0 * W + ix0) * 256 + c8));
          const short8 u01 = *(const short8*)(clb + ((size_t)(iy0 * W + ix1) * 256 + c8));
          const short8 u10 = *(const short8*)(clb + ((size_t)(iy1 * W + ix0) * 256 + c8));
          const short8 u11 = *(const short8*)(clb + ((size_t)(iy1 * W + ix1) * 256 + c8));
#pragma unroll
          for (int i = 0; i < 8; ++i) {
            a[i] += w00 * bf2f((ushort_t)u00[i]) + w01 * bf2f((ushort_t)u01[i]) +
                    w10 * bf2f((ushort_t)u10[i]) + w11 * bf2f((ushort_t)u11[i]);
          }
        }
      }
      short8 pv;
#pragma unroll
      for (int i = 0; i < 8; ++i) pv[i] = (short)f2bf(a[i] * 0.25f);
      *(short8*)&s_pool[(rr * 50 + pos) * POOL_PITCH + c8] = pv;
    }
  }
  __syncthreads();  // pool + zero rows visible to all waves

  // ---- MFMA conv: barrier-free K-loop, A direct from global ---------------
  const int ml = l & 31;
  const int quad = l >> 5;
  const int co_base = w * 32;

  const int pA = ml;
  const int pB = ml + 32;
  const int pyA = pA / 7, pxA = pA % 7;
  const int pyB = pB / 7, pxB = pB % 7;

  floatx16 acc[4];
#pragma unroll
  for (int a = 0; a < 4; ++a)
#pragma unroll
    for (int i = 0; i < 16; ++i) acc[a][i] = 0.f;

  const ushort_t* a0p = wr + (co_base + ml) * 16 + quad * 8;

  int kk = 0;
  for (int j = 0; j < 9; ++j) {
    const int dy = j / 3 - 1, dx = j % 3 - 1;
    int bnA, bnB;
    {
      const int ry = pyA + dy, rx = pxA + dx;
      const bool ok = (ry >= 0) & (ry < 7) & (rx >= 0) & (rx < 7);
      bnA = ok ? ry * 7 + rx : 49;
    }
    {
      const int ry = pyB + dy, rx = pxB + dx;
      const bool ok = (pB < 49) & (ry >= 0) & (ry < 7) & (rx >= 0) & (rx < 7);
      bnB = ok ? ry * 7 + rx : 49;
    }
    const int row0 = bnA, row1 = bnB, row2 = 50 + bnA, row3 = 50 + bnB;

#pragma unroll 4
    for (int kc = 0; kc < 16; ++kc, ++kk) {
      const short8 a0 = *(const short8*)(a0p + kk * 4096);
      const int cof = kc * 16 + quad * 8;
      const short8 b0 = *(const short8*)&s_pool[row0 * POOL_PITCH + cof];
      const short8 b1 = *(const short8*)&s_pool[row1 * POOL_PITCH + cof];
      const short8 b2 = *(const short8*)&s_pool[row2 * POOL_PITCH + cof];
      const short8 b3 = *(const short8*)&s_pool[row3 * POOL_PITCH + cof];
      acc[0] = __builtin_amdgcn_mfma_f32_32x32x16_bf16(a0, b0, acc[0], 0, 0, 0);
      acc[1] = __builtin_amdgcn_mfma_f32_32x32x16_bf16(a0, b1, acc[1], 0, 0, 0);
      acc[2] = __builtin_amdgcn_mfma_f32_32x32x16_bf16(a0, b2, acc[2], 0, 0, 0);
      acc[3] = __builtin_amdgcn_mfma_f32_32x32x16_bf16(a0, b3, acc[3], 0, 0, 0);
    }
  }
  __syncthreads();  // all pool reads done before h overwrites it

  // ---- epilogue: bias + relu -> h in LDS (fc-k order: [rr][co*49+pos]) ----
  ushort_t* h_lds = s_pool;
#pragma unroll
  for (int reg = 0; reg < 16; ++reg) {
    const int co = co_base + (reg & 3) + 8 * (reg >> 2) + 4 * quad;
    const float cb = conv_b[co];
    const int base = co * 49;
    h_lds[base + pA] = f2bf(fmaxf(acc[0][reg] + cb, 0.f));
    h_lds[12544 + base + pA] = f2bf(fmaxf(acc[2][reg] + cb, 0.f));
    if (pB < 49) {
      h_lds[base + pB] = f2bf(fmaxf(acc[1][reg] + cb, 0.f));
      h_lds[12544 + base + pB] = f2bf(fmaxf(acc[3][reg] + cb, 0.f));
    }
  }
  __syncthreads();

  // ---- FC(12544 -> 21) via MFMA 16x16x32, K-split across 8 waves ----------
  // A = fc_w (rows = classes, clamped to 20), B cols 0/1 = h of roi 0/1
  // (cols 2..15 read roi (n&1) data -> garbage, discarded).
  {
    const int n = l & 15;             // C/D col; valid cols 0,1
    const int kq = (l >> 4) * 8;      // k-offset within K=32
    const int cls0 = min(n, 20);      // tile 0 class row
    const int cls1 = min(16 + n, 20); // tile 1 class row
    const ushort_t* ap0 = fwb + (size_t)cls0 * 12544 + kq;
    const ushort_t* ap1 = fwb + (size_t)cls1 * 12544 + kq;
    const ushort_t* bp = h_lds + (size_t)(l & 1) * 12544 + kq;
    const int kbase = w * 1568;

    floatx4 fa0, fa1;
#pragma unroll
    for (int i = 0; i < 4; ++i) { fa0[i] = 0.f; fa1[i] = 0.f; }

    for (int it = 0; it < 49; ++it) {
      const int k = kbase + it * 32;
      const short8 av0 = *(const short8*)(ap0 + k);
      const short8 av1 = *(const short8*)(ap1 + k);
      const short8 bv = *(const short8*)(bp + k);
      fa0 = __builtin_amdgcn_mfma_f32_16x16x32_bf16(av0, bv, fa0, 0, 0, 0);
      fa1 = __builtin_amdgcn_mfma_f32_16x16x32_bf16(av1, bv, fa1, 0, 0, 0);
    }
    // C/D layout: col = l&15, row = (l>>4)*4 + reg
    if (n < 2) {
      const int m4 = (l >> 4) * 4;
#pragma unroll
      for (int reg = 0; reg < 4; ++reg) {
        s_fcred[((m4 + reg) * 2 + n) * 8 + w] = fa0[reg];
        s_fcred[((16 + m4 + reg) * 2 + n) * 8 + w] = fa1[reg];
      }
    }
  }
  __syncthreads();
  if (t < 2 * NCLS) {
    const int cls = t >> 1;
    const int rr = t & 1;
    const float* pr = &s_fcred[(cls * 2 + rr) * 8];
    float s = pr[0] + pr[1] + pr[2] + pr[3] + pr[4] + pr[5] + pr[6] + pr[7];
    out[(size_t)(g * 2 + rr) * NCLS + cls] = s + fc_b[cls];
  }
}

extern "C" void kernel_launch(void* const* d_in, const int* in_sizes, int n_in,
                              void* d_out, int out_size, void* d_ws,
                              size_t ws_size, hipStream_t stream) {
  const float* f3 = (const float*)d_in[0];
  const float* f4 = (const float*)d_in[1];
  const float* f5 = (const float*)d_in[2];
  const float* p3 = (const float*)d_in[3];
  const float* p4 = (const float*)d_in[4];
  const float* p5 = (const float*)d_in[5];
  const float* gt = (const float*)d_in[6];
  const float* cw = (const float*)d_in[7];
  const float* cb = (const float*)d_in[8];
  const float* fw = (const float*)d_in[9];
  const float* fb = (const float*)d_in[10];
  float* out = (float*)d_out;

  ushort_t* wsp = (ushort_t*)d_ws;
  ushort_t* wr = wsp;
  ushort_t* fwb = wsp + OFF_FWB;
  ushort_t* cl3 = wsp + OFF_CL3;
  ushort_t* cl4 = wsp + OFF_CL4;
  ushort_t* cl5 = wsp + OFF_CL5;

  prep_kernel<<<972, 256, 0, stream>>>(cw, fw, f3, f4, f5, p3, p4, p5, gt, wr,
                                       fwb, cl3, cl4, cl5, out);
  cls_head_kernel<<<NROI_TOT / 2, 512, 0, stream>>>(cl3, cl4, cl5, p3, p4, p5,
                                                    wr, cb, fwb, fb, out);
}

// Round 8
// 368.770 us; speedup vs baseline: 8.5064x; 1.0672x over previous
//
#include <hip/hip_runtime.h>

typedef unsigned short ushort_t;
typedef __attribute__((ext_vector_type(4))) unsigned short ushort4_t;
typedef __attribute__((ext_vector_type(8))) short short8;
typedef __attribute__((ext_vector_type(4))) unsigned int uint4v;
typedef __attribute__((ext_vector_type(2))) float float2v;
typedef __attribute__((ext_vector_type(4))) float floatx4;
typedef __attribute__((ext_vector_type(16))) float floatx16;

#define B_ 4
#define C_ 256
#define R_ 256
#define M_ 40
#define NCLS 21
#define ROI_ 7
#define G_ 14
#define NROI_TOT 3072
#define PROPS_PER_IMG 768
#define POOL_PITCH 264   // ushorts per pool row (528 B, 16B-aligned)
#define WCONV_ELEMS (256 * 2304)   // = 144 chunks * 4096
#define NKB 392                    // 12544 / 32 k-blocks for FC
#define WFC2_ELEMS (NKB * 32 * 32) // padded 32 classes, fragment-ordered
// ws layout (ushort offsets)
#define OFF_FWB   WCONV_ELEMS
#define OFF_CL3   (OFF_FWB + WFC2_ELEMS)
#define OFF_CL4   (OFF_CL3 + 4 * 64 * 64 * 256)
#define OFF_CL5   (OFF_CL4 + 4 * 32 * 32 * 256)

__device__ __forceinline__ ushort_t f2bf(float f) {
  unsigned u = __builtin_bit_cast(unsigned, f);
  u += 0x7fff + ((u >> 16) & 1);  // RNE
  return (ushort_t)(u >> 16);
}
__device__ __forceinline__ float bf2f(ushort_t h) {
  unsigned u = ((unsigned)h) << 16;
  return __builtin_bit_cast(float, u);
}
// two packed bf16 (one dword) -> float2 {low half, high half}
__device__ __forceinline__ float2v cvt2(unsigned u) {
  float2v r;
  r[0] = __builtin_bit_cast(float, u << 16);
  r[1] = __builtin_bit_cast(float, u & 0xffff0000u);
  return r;
}

// ---------------------------------------------------------------------------
// K0 (merged): blocks [0,512): conv_w -> bf16 chunk-major wr2[kk][co][i];
//   fc_w -> bf16 MFMA-A-fragment order fwb2[kb][cls32][kq][8] (cls>20 = 0);
//   blocks [512,960): feats fp32 NCHW -> bf16 NHWC;
//   blocks [960,972): IoU matching.
// ---------------------------------------------------------------------------
__global__ __launch_bounds__(256) void prep_kernel(
    const float* __restrict__ cw, const float* __restrict__ fw,
    const float* __restrict__ f3, const float* __restrict__ f4,
    const float* __restrict__ f5, const float* __restrict__ p3,
    const float* __restrict__ p4, const float* __restrict__ p5,
    const float* __restrict__ gt, ushort_t* __restrict__ wr,
    ushort_t* __restrict__ fwb, ushort_t* __restrict__ cl3,
    ushort_t* __restrict__ cl4, ushort_t* __restrict__ cl5,
    float* __restrict__ out) {
  __shared__ ushort_t tile[64 * 257];
  const int id = blockIdx.x;
  const int t = threadIdx.x;

  if (id < 512) {
    // ---- conv weights: chunk-major ----
    const int i0 = id * 256 + t;
    const int stride = 512 * 256;
    for (int idx = i0; idx < WCONV_ELEMS; idx += stride) {
      const int kk = idx >> 12;
      const int rem = idx & 4095;
      const int co = rem >> 4;
      const int i = rem & 15;
      const int k = kk * 16 + i;
      const int j = k >> 8;
      const int ci = k & 255;
      wr[idx] = f2bf(cw[(co * 256 + ci) * 9 + j]);
    }
    // ---- fc weights: A-fragment order, 32 padded class rows ----
    for (int idx = i0; idx < WFC2_ELEMS; idx += stride) {
      const int kb = idx >> 10;
      const int rem = idx & 1023;
      const int cls = rem >> 5;
      const int koff = rem & 31;
      fwb[idx] =
          (cls < NCLS) ? f2bf(fw[(size_t)cls * 12544 + kb * 32 + koff]) : 0;
    }
  } else if (id < 960) {
    // ---- features NCHW -> NHWC bf16 ----
    const int fid = id - 512;
    const float* in;
    ushort_t* outp;
    int b, y, W;
    if (fid < 256) { in = f3; outp = cl3; W = 64; b = fid >> 6; y = fid & 63; }
    else if (fid < 384) { in = f4; outp = cl4; W = 32; b = (fid - 256) >> 5; y = (fid - 256) & 31; }
    else { in = f5; outp = cl5; W = 16; b = (fid - 384) >> 4; y = (fid - 384) & 15; }

    for (int idx = t; idx < 256 * W; idx += 256) {
      const int c = idx / W;
      const int x = idx - c * W;
      tile[x * 257 + c] = f2bf(in[((size_t)(b * 256 + c) * W + y) * W + x]);
    }
    __syncthreads();
    ushort_t* orow = outp + ((size_t)(b * W + y) * W) * 256;
    for (int idx = t; idx < W * 64; idx += 256) {
      const int x = idx >> 6;
      const int c4 = (idx & 63) * 4;
      ushort4_t v;
      v[0] = tile[x * 257 + c4 + 0];
      v[1] = tile[x * 257 + c4 + 1];
      v[2] = tile[x * 257 + c4 + 2];
      v[3] = tile[x * 257 + c4 + 3];
      *(ushort4_t*)(orow + (size_t)x * 256 + c4) = v;
    }
  } else {
    // ---- matching ----
    const int gidx = (id - 960) * 256 + t;
    if (gidx >= NROI_TOT) return;
    const int b = gidx / PROPS_PER_IMG;
    const int i = gidx - b * PROPS_PER_IMG;
    const int lvl = i >> 8;
    const int r = i & 255;
    const float* prop =
        (lvl == 0 ? p3 : (lvl == 1 ? p4 : p5)) + (size_t)(b * R_ + r) * 4;
    const float px1 = prop[0], py1 = prop[1], px2 = prop[2], py2 = prop[3];
    const float a1 = (px2 - px1) * (py2 - py1);
    const float* gtb = gt + (size_t)b * M_ * 5;

    float best = -2.f;
    int bi = 0;
    for (int j = 0; j < M_; ++j) {
      const float gx1 = gtb[j * 5 + 0], gy1 = gtb[j * 5 + 1];
      const float gx2 = gtb[j * 5 + 2], gy2 = gtb[j * 5 + 3];
      const float cls = gtb[j * 5 + 4];
      const float tlx = fmaxf(px1, gx1), tly = fmaxf(py1, gy1);
      const float brx = fminf(px2, gx2), bry = fminf(py2, gy2);
      const float iw = fmaxf(brx - tlx, 0.f), ih = fmaxf(bry - tly, 0.f);
      const float inter = iw * ih;
      const float a2 = (gx2 - gx1) * (gy2 - gy1);
      const float iou = inter / ((a1 + a2) - inter);
      const float m = (cls != -1.0f) ? iou : -1.0f;
      if (m > best) { best = m; bi = j; }
    }
    float o0, o1, o2, o3, o4;
    if (best <= 0.4f) {
      o0 = o1 = o2 = o3 = o4 = -1.0f;
    } else if (best < 0.6f) {
      o0 = o1 = o2 = o3 = o4 = -1e8f;
    } else {
      o0 = gtb[bi * 5 + 0]; o1 = gtb[bi * 5 + 1]; o2 = gtb[bi * 5 + 2];
      o3 = gtb[bi * 5 + 3]; o4 = gtb[bi * 5 + 4];
    }
    float* od = out + (size_t)NROI_TOT * NCLS + (size_t)gidx * 5;
    od[0] = o0; od[1] = o1; od[2] = o2; od[3] = o3; od[4] = o4;
  }
}

// ---------------------------------------------------------------------------
// K1: fused roi-align -> barrier-free MFMA conv3x3 -> relu -> MFMA FC.
//     512 threads (8 waves) per block, 2 rois per block.
//     XCD-aware swizzle: image = (bid&7)>>1 so one image's features stay
//     resident in that XCD's 4 MB L2.
// ---------------------------------------------------------------------------
__global__ __launch_bounds__(512, 4) void cls_head_kernel(
    const ushort_t* __restrict__ cl3, const ushort_t* __restrict__ cl4,
    const ushort_t* __restrict__ cl5, const float* __restrict__ p3,
    const float* __restrict__ p4, const float* __restrict__ p5,
    const ushort_t* __restrict__ wr, const float* __restrict__ conv_b,
    const ushort_t* __restrict__ fwb, const float* __restrict__ fc_b,
    float* __restrict__ out) {
  __shared__ __align__(16) ushort_t s_pool[2 * 50 * POOL_PITCH];  // 52.8 KB
  __shared__ int s_iy0[28], s_iy1[28], s_ix0[28], s_ix1[28];
  __shared__ float s_ly[28], s_lx[28], s_vy[28], s_vx[28];
  __shared__ float s_fcred[512];  // [class(32)][roi(2)][wave(8)]

  const int bid = blockIdx.x;
  const int t = threadIdx.x;

  // XCD-locality swizzle: blocks with (bid&7)>>1 == img handle image img.
  const int img = (bid & 7) >> 1;
  const int pair = (bid >> 3) * 2 + (bid & 1);  // 0..383 within image
  const int rid0 = img * PROPS_PER_IMG + pair * 2;

  // per-roi metadata
  const ushort_t* clb_[2];
  int W_[2];
  const float* prop_[2];
#pragma unroll
  for (int rr = 0; rr < 2; ++rr) {
    const int rid = rid0 + rr;
    const int b = rid / PROPS_PER_IMG;
    const int rem = rid - b * PROPS_PER_IMG;
    const int lvl = rem >> 8;
    const int r = rem & 255;
    const ushort_t* base;
    const float* pp;
    int Wl;
    if (lvl == 0) { base = cl3; pp = p3; Wl = 64; }
    else if (lvl == 1) { base = cl4; pp = p4; Wl = 32; }
    else { base = cl5; pp = p5; Wl = 16; }
    clb_[rr] = base + (size_t)b * Wl * Wl * 256;
    W_[rr] = Wl;
    prop_[rr] = pp + (size_t)(b * R_ + r) * 4;
  }

  // zero rows 49/99 (im2col zero-row per roi)
  if (t < POOL_PITCH) {
    s_pool[49 * POOL_PITCH + t] = 0;
    s_pool[99 * POOL_PITCH + t] = 0;
  }

  // ---- axis tables for both rois ------------------------------------------
  if (t < 56) {
    const int rr = t / 28;
    const int tt = t - rr * 28;
    const float* prop = prop_[rr];
    const int H = W_[rr];
    const float scale = 1.0f / (float)(H == 64 ? 8 : (H == 32 ? 16 : 32));
    const float bx1 = prop[0], by1 = prop[1], bx2 = prop[2], by2 = prop[3];
    const float ax = bx1 * scale - 0.5f;
    const float ay = by1 * scale - 0.5f;
    const float rw = bx2 * scale - 0.5f - ax;
    const float rh = by2 * scale - 0.5f - ay;
    const int i = (tt < G_) ? tt : (tt - G_);
    const float frac = ((float)i + 0.5f) / (float)G_;
    const int o = rr * G_ + i;
    if (tt < G_) {
      float yy = ay + frac * rh;
      float v = (yy >= -1.0f && yy <= (float)H) ? 1.0f : 0.0f;
      float y = fminf(fmaxf(yy, 0.0f), (float)(H - 1));
      float y0f = floorf(y);
      int y0 = (int)y0f;
      s_iy0[o] = y0;
      s_iy1[o] = min(y0 + 1, H - 1);
      s_ly[o] = y - y0f;
      s_vy[o] = v;
    } else {
      float xx = ax + frac * rw;
      float v = (xx >= -1.0f && xx <= (float)H) ? 1.0f : 0.0f;
      float x = fminf(fmaxf(xx, 0.0f), (float)(H - 1));
      float x0f = floorf(x);
      int x0 = (int)x0f;
      s_ix0[o] = x0;
      s_ix1[o] = min(x0 + 1, H - 1);
      s_lx[o] = x - x0f;
      s_vx[o] = v;
    }
  }
  __syncthreads();

  const int l = t & 63;
  const int w = t >> 6;  // 0..7

  // ---- roi-align: half-wave per cell, lane = 8 channels, packed f32 math --
  {
    const int hw = l >> 5;        // which cell of the pair
    const int c8 = (l & 31) * 8;  // channel offset
    for (int cb = w * 2; cb < 98; cb += 16) {
      const int cell = cb + hw;
      if (cell >= 98) continue;
      const int rr = (cell >= 49) ? 1 : 0;
      const int pos = cell - rr * 49;
      const int py = pos / 7, px = pos - (pos / 7) * 7;
      const ushort_t* clb = clb_[rr];
      const int W = W_[rr];
      float2v a01 = {0.f, 0.f}, a23 = {0.f, 0.f};
      float2v a45 = {0.f, 0.f}, a67 = {0.f, 0.f};
#pragma unroll
      for (int sy = 0; sy < 2; ++sy) {
        const int gy = rr * G_ + 2 * py + sy;
        const int iy0 = s_iy0[gy], iy1 = s_iy1[gy];
        const float ly = s_ly[gy], vy = s_vy[gy];
        const float hy = 1.0f - ly;
#pragma unroll
        for (int sx = 0; sx < 2; ++sx) {
          const int gx = rr * G_ + 2 * px + sx;
          const int ix0 = s_ix0[gx], ix1 = s_ix1[gx];
          const float lx = s_lx[gx], vx = s_vx[gx];
          const float hx = 1.0f - lx;
          const float vv = vy * vx;
          const float w00 = vv * hy * hx, w01 = vv * hy * lx;
          const float w10 = vv * ly * hx, w11 = vv * ly * lx;
          const uint4v u00 = *(const uint4v*)(clb + ((size_t)(iy0 * W + ix0) * 256 + c8));
          const uint4v u01 = *(const uint4v*)(clb + ((size_t)(iy0 * W + ix1) * 256 + c8));
          const uint4v u10 = *(const uint4v*)(clb + ((size_t)(iy1 * W + ix0) * 256 + c8));
          const uint4v u11 = *(const uint4v*)(clb + ((size_t)(iy1 * W + ix1) * 256 + c8));
          a01 += cvt2(u00[0]) * w00 + cvt2(u01[0]) * w01 +
                 cvt2(u10[0]) * w10 + cvt2(u11[0]) * w11;
          a23 += cvt2(u00[1]) * w00 + cvt2(u01[1]) * w01 +
                 cvt2(u10[1]) * w10 + cvt2(u11[1]) * w11;
          a45 += cvt2(u00[2]) * w00 + cvt2(u01[2]) * w01 +
                 cvt2(u10[2]) * w10 + cvt2(u11[2]) * w11;
          a67 += cvt2(u00[3]) * w00 + cvt2(u01[3]) * w01 +
                 cvt2(u10[3]) * w10 + cvt2(u11[3]) * w11;
        }
      }
      short8 pv;
      pv[0] = (short)f2bf(a01[0] * 0.25f);
      pv[1] = (short)f2bf(a01[1] * 0.25f);
      pv[2] = (short)f2bf(a23[0] * 0.25f);
      pv[3] = (short)f2bf(a23[1] * 0.25f);
      pv[4] = (short)f2bf(a45[0] * 0.25f);
      pv[5] = (short)f2bf(a45[1] * 0.25f);
      pv[6] = (short)f2bf(a67[0] * 0.25f);
      pv[7] = (short)f2bf(a67[1] * 0.25f);
      *(short8*)&s_pool[(rr * 50 + pos) * POOL_PITCH + c8] = pv;
    }
  }
  __syncthreads();  // pool + zero rows visible to all waves

  // ---- MFMA conv: barrier-free K-loop, A direct from global ---------------
  const int ml = l & 31;
  const int quad = l >> 5;
  const int co_base = w * 32;

  const int pA = ml;
  const int pB = ml + 32;
  const int pyA = pA / 7, pxA = pA % 7;
  const int pyB = pB / 7, pxB = pB % 7;

  floatx16 acc[4];
#pragma unroll
  for (int a = 0; a < 4; ++a)
#pragma unroll
    for (int i = 0; i < 16; ++i) acc[a][i] = 0.f;

  const ushort_t* a0p = wr + (co_base + ml) * 16 + quad * 8;

  int kk = 0;
  for (int j = 0; j < 9; ++j) {
    const int dy = j / 3 - 1, dx = j % 3 - 1;
    int bnA, bnB;
    {
      const int ry = pyA + dy, rx = pxA + dx;
      const bool ok = (ry >= 0) & (ry < 7) & (rx >= 0) & (rx < 7);
      bnA = ok ? ry * 7 + rx : 49;
    }
    {
      const int ry = pyB + dy, rx = pxB + dx;
      const bool ok = (pB < 49) & (ry >= 0) & (ry < 7) & (rx >= 0) & (rx < 7);
      bnB = ok ? ry * 7 + rx : 49;
    }
    const int row0 = bnA, row1 = bnB, row2 = 50 + bnA, row3 = 50 + bnB;

#pragma unroll 4
    for (int kc = 0; kc < 16; ++kc, ++kk) {
      const short8 a0 = *(const short8*)(a0p + kk * 4096);
      const int cof = kc * 16 + quad * 8;
      const short8 b0 = *(const short8*)&s_pool[row0 * POOL_PITCH + cof];
      const short8 b1 = *(const short8*)&s_pool[row1 * POOL_PITCH + cof];
      const short8 b2 = *(const short8*)&s_pool[row2 * POOL_PITCH + cof];
      const short8 b3 = *(const short8*)&s_pool[row3 * POOL_PITCH + cof];
      acc[0] = __builtin_amdgcn_mfma_f32_32x32x16_bf16(a0, b0, acc[0], 0, 0, 0);
      acc[1] = __builtin_amdgcn_mfma_f32_32x32x16_bf16(a0, b1, acc[1], 0, 0, 0);
      acc[2] = __builtin_amdgcn_mfma_f32_32x32x16_bf16(a0, b2, acc[2], 0, 0, 0);
      acc[3] = __builtin_amdgcn_mfma_f32_32x32x16_bf16(a0, b3, acc[3], 0, 0, 0);
    }
  }
  __syncthreads();  // all pool reads done before h overwrites it

  // ---- epilogue: bias + relu -> h in LDS (fc-k order: [rr][co*49+pos]) ----
  ushort_t* h_lds = s_pool;
#pragma unroll
  for (int reg = 0; reg < 16; ++reg) {
    const int co = co_base + (reg & 3) + 8 * (reg >> 2) + 4 * quad;
    const float cb = conv_b[co];
    const int base = co * 49;
    h_lds[base + pA] = f2bf(fmaxf(acc[0][reg] + cb, 0.f));
    h_lds[12544 + base + pA] = f2bf(fmaxf(acc[2][reg] + cb, 0.f));
    if (pB < 49) {
      h_lds[base + pB] = f2bf(fmaxf(acc[1][reg] + cb, 0.f));
      h_lds[12544 + base + pB] = f2bf(fmaxf(acc[3][reg] + cb, 0.f));
    }
  }
  __syncthreads();

  // ---- FC(12544 -> 21) via MFMA 16x16x32, K-split across 8 waves ----------
  // A from fwb2 fragment order (coalesced 1 KB/wave); B cols 0/1 = roi 0/1.
  {
    const int n = l & 15;        // C/D col; valid cols 0,1
    const int kq = l >> 4;       // 0..3
    // lane offsets inside a 1024-elem kb block: tile0 cls=n, tile1 cls=16+n
    const ushort_t* ap0 = fwb + (n * 4 + kq) * 8;
    const ushort_t* ap1 = ap0 + 512;
    const ushort_t* bp = h_lds + (size_t)(l & 1) * 12544 + kq * 8;
    const int kb0 = w * 49;

    floatx4 fa0, fa1;
#pragma unroll
    for (int i = 0; i < 4; ++i) { fa0[i] = 0.f; fa1[i] = 0.f; }

    for (int it = 0; it < 49; ++it) {
      const int kb = kb0 + it;
      const short8 av0 = *(const short8*)(ap0 + kb * 1024);
      const short8 av1 = *(const short8*)(ap1 + kb * 1024);
      const short8 bv = *(const short8*)(bp + kb * 32);
      fa0 = __builtin_amdgcn_mfma_f32_16x16x32_bf16(av0, bv, fa0, 0, 0, 0);
      fa1 = __builtin_amdgcn_mfma_f32_16x16x32_bf16(av1, bv, fa1, 0, 0, 0);
    }
    // C/D layout: col = l&15, row = (l>>4)*4 + reg
    if (n < 2) {
      const int m4 = kq * 4;
#pragma unroll
      for (int reg = 0; reg < 4; ++reg) {
        s_fcred[((m4 + reg) * 2 + n) * 8 + w] = fa0[reg];
        s_fcred[((16 + m4 + reg) * 2 + n) * 8 + w] = fa1[reg];
      }
    }
  }
  __syncthreads();
  if (t < 2 * NCLS) {
    const int cls = t >> 1;
    const int rr = t & 1;
    const float* pr = &s_fcred[(cls * 2 + rr) * 8];
    float s = pr[0] + pr[1] + pr[2] + pr[3] + pr[4] + pr[5] + pr[6] + pr[7];
    out[(size_t)(rid0 + rr) * NCLS + cls] = s + fc_b[cls];
  }
}

extern "C" void kernel_launch(void* const* d_in, const int* in_sizes, int n_in,
                              void* d_out, int out_size, void* d_ws,
                              size_t ws_size, hipStream_t stream) {
  const float* f3 = (const float*)d_in[0];
  const float* f4 = (const float*)d_in[1];
  const float* f5 = (const float*)d_in[2];
  const float* p3 = (const float*)d_in[3];
  const float* p4 = (const float*)d_in[4];
  const float* p5 = (const float*)d_in[5];
  const float* gt = (const float*)d_in[6];
  const float* cw = (const float*)d_in[7];
  const float* cb = (const float*)d_in[8];
  const float* fw = (const float*)d_in[9];
  const float* fb = (const float*)d_in[10];
  float* out = (float*)d_out;

  ushort_t* wsp = (ushort_t*)d_ws;
  ushort_t* wr = wsp;
  ushort_t* fwb = wsp + OFF_FWB;
  ushort_t* cl3 = wsp + OFF_CL3;
  ushort_t* cl4 = wsp + OFF_CL4;
  ushort_t* cl5 = wsp + OFF_CL5;

  prep_kernel<<<972, 256, 0, stream>>>(cw, fw, f3, f4, f5, p3, p4, p5, gt, wr,
                                       fwb, cl3, cl4, cl5, out);
  cls_head_kernel<<<NROI_TOT / 2, 512, 0, stream>>>(cl3, cl4, cl5, p3, p4, p5,
                                                    wr, cb, fwb, fb, out);
}